// Round 12
// baseline (211.333 us; speedup 1.0000x reference)
//
#include <hip/hip_runtime.h>

typedef short bf16x8 __attribute__((ext_vector_type(8)));
typedef float f32x4 __attribute__((ext_vector_type(4)));
typedef unsigned short ushort_t;
typedef unsigned int uint_t;

#define DIM 2048
#define NH 16
#define HD 128

__device__ __forceinline__ ushort_t f2b(float f) {
    union { float f; uint_t u; } a; a.f = f;
    uint_t u = a.u;
    return (ushort_t)((u + 0x7fffu + ((u >> 16) & 1u)) >> 16);
}

__device__ __forceinline__ float b2f(ushort_t s) {
    union { uint_t u; float f; } a; a.u = ((uint_t)s) << 16;
    return a.f;
}

__device__ __forceinline__ uint_t cvt_pk_bf16(float lo, float hi) {
    uint_t r;
    asm("v_cvt_pk_bf16_f32 %0, %1, %2" : "=v"(r) : "v"(lo), "v"(hi));
    return r;
}

__device__ __forceinline__ void gload_lds16(const void* g, void* l) {
    void* gg = const_cast<void*>(g);
    __builtin_amdgcn_global_load_lds(
        (__attribute__((address_space(1))) uint_t*)gg,
        (__attribute__((address_space(3))) uint_t*)l, 16, 0, 0);
}

// ---------------- all fp32->bf16 converts in ONE dispatch ----------------
struct Cvt9 { const float* s[9]; ushort_t* d[9]; int n[9]; };
__global__ __launch_bounds__(256) void k_cvt9(Cvt9 a) {
    int y = blockIdx.y;
    const float* in = a.s[y];
    ushort_t* out = a.d[y];
    int n = a.n[y];
    for (int idx = (blockIdx.x * 256 + threadIdx.x) * 8; idx < n; idx += 2048 * 256 * 8) {
        float4 p = *(const float4*)(in + idx);
        float4 q = *(const float4*)(in + idx + 4);
        uint4 o;
        o.x = (uint_t)f2b(p.x) | ((uint_t)f2b(p.y) << 16);
        o.y = (uint_t)f2b(p.z) | ((uint_t)f2b(p.w) << 16);
        o.z = (uint_t)f2b(q.x) | ((uint_t)f2b(q.y) << 16);
        o.w = (uint_t)f2b(q.z) | ((uint_t)f2b(q.w) << 16);
        *(uint4*)(out + idx) = o;
    }
}

struct G8 {
    const ushort_t* A;
    const ushort_t* B;
    const float* bias0;
    const float* bias1;
    void* out0;
    void* out1;
};

// ======== 4-phase 256x256x(BK=64) bf16 NT GEMM (merged QKV), 1024 thr, 128KB LDS ========
// 16 waves (4x4), per-wave 64x64, acc[4][4]. Staging ledger (race-free):
//   p1(reads b0) -> b1.A<-Tb ; p2(reads b0) -> b1.B<-Tb, vmcnt(0)
//   p3(reads b1) -> b0.A<-Ta2; p4(reads b1) -> b0.B<-Ta2, vmcnt(0)
// No region is staged in a phase that reads it; every staged region's last
// reader completed (lgkm before MFMA) >=1 barrier earlier.
// B rows rho-permuted within 32 so lane c owns cols {c*2,c*2+1} per window.
__global__ __launch_bounds__(1024, 1) void k_g256(G8 p0, G8 p1, G8 p2) {
    extern __shared__ __align__(16) char sm[];
    int tid = threadIdx.x, lane = tid & 63, w = tid >> 6;
    int c = lane & 15, g = lane >> 4;
    int wr = w >> 2, wc = w & 3;

    int flat = blockIdx.x;
    G8 ar;
    int bm, bn, isKV = 0, kvoff = 0;
    {
        int re = (flat & 7) * 32 + (flat >> 3);
        if (re < 128) { ar = p0; bm = re & 15; bn = re >> 4; }
        else {
            int r2 = re - 128;
            int z = r2 >> 6; r2 &= 63;
            ar = z ? p2 : p1;
            bm = r2 & 3; bn = r2 >> 2;
            isKV = 1; kvoff = z ? 512 : 0;
        }
    }

    // ---- staging: thread -> (row_local = tid>>3, chunk = lane&7); LDS dest linear tid*16 ----
    int row_local = tid >> 3;
    int l3 = lane >> 3;
    int swz = ((lane & 7) ^ l3) << 4;
    // A half h holds global rows [h*128, h*128+128)
    const char* srcA[2];
#pragma unroll
    for (int h = 0; h < 2; h++)
        srcA[h] = (const char*)ar.A + (size_t)(bm * 256 + h * 128 + row_local) * 4096 + swz;
    // B half h: LDS row r <- global row h*128 + (r>>5)*32 + rho(r&31)
    const char* srcB[2];
#pragma unroll
    for (int h = 0; h < 2; h++) {
        int x = h * 128 + row_local;
        int grp = x >> 5, j = x & 31;
        int gr = grp * 32 + (j & 15) * 2 + (j >> 4);
        srcB[h] = (const char*)ar.B + (size_t)(bn * 256 + gr) * 4096 + swz;
    }
    char* dstW = sm + w * 1024;   // + buf + region offset (wave-uniform)

    auto SAh = [&](int buf, int h, int t) {
        gload_lds16(srcA[h] + (size_t)t * 128, dstW + buf + h * 16384);
    };
    auto SBh = [&](int buf, int h, int t) {
        gload_lds16(srcB[h] + (size_t)t * 128, dstW + buf + 32768 + h * 16384);
    };

    // ---- read offsets ----
    int bKS0 = (g << 4) ^ ((c & 7) << 4);
    int bKS1 = (64 | (g << 4)) ^ ((c & 7) << 4);
    int aBase = (wr >> 1) * 16384 + ((wr & 1) * 64 + c) * 128;           // + m*2048 + bKS
    int bBase = 32768 + (wc >> 1) * 16384 + ((wc & 1) * 64 + c) * 128;   // + n*2048 + bKS

    f32x4 acc[4][4];
#pragma unroll
    for (int m = 0; m < 4; m++)
#pragma unroll
        for (int n = 0; n < 4; n++) acc[m][n] = (f32x4){0.f, 0.f, 0.f, 0.f};

    const int B1 = 65536;

    auto PH_START = [&](int buf, int nh, bf16x8 (&a0)[4], bf16x8 (&b0v)[2]) {
#pragma unroll
        for (int m = 0; m < 4; m++)
            a0[m] = *(const bf16x8*)(sm + buf + aBase + m * 2048 + bKS0);
#pragma unroll
        for (int n2 = 0; n2 < 2; n2++)
            b0v[n2] = *(const bf16x8*)(sm + buf + bBase + (nh * 2 + n2) * 2048 + bKS0);
    };
    auto PH_END = [&](int buf, int nh, bf16x8 (&a0)[4], bf16x8 (&b0v)[2]) {
        __builtin_amdgcn_s_setprio(1);
#pragma unroll
        for (int m = 0; m < 4; m++)
#pragma unroll
            for (int n2 = 0; n2 < 2; n2++)
                acc[m][nh * 2 + n2] = __builtin_amdgcn_mfma_f32_16x16x32_bf16(
                    a0[m], b0v[n2], acc[m][nh * 2 + n2], 0, 0, 0);
        bf16x8 a1[4], b1v[2];
#pragma unroll
        for (int m = 0; m < 4; m++)
            a1[m] = *(const bf16x8*)(sm + buf + aBase + m * 2048 + bKS1);
#pragma unroll
        for (int n2 = 0; n2 < 2; n2++)
            b1v[n2] = *(const bf16x8*)(sm + buf + bBase + (nh * 2 + n2) * 2048 + bKS1);
#pragma unroll
        for (int m = 0; m < 4; m++)
#pragma unroll
            for (int n2 = 0; n2 < 2; n2++)
                acc[m][nh * 2 + n2] = __builtin_amdgcn_mfma_f32_16x16x32_bf16(
                    a1[m], b1v[n2], acc[m][nh * 2 + n2], 0, 0, 0);
        __builtin_amdgcn_s_setprio(0);
    };

    // ---- prologue: b0 <- T0 only ----
    SAh(0, 0, 0); SAh(0, 1, 0); SBh(0, 0, 0); SBh(0, 1, 0);
    asm volatile("s_waitcnt vmcnt(0)" ::: "memory");
    __builtin_amdgcn_s_barrier();

#pragma unroll 1
    for (int i = 0; i < 16; ++i) {
        int Tb  = 2 * i + 1;
        int Ta2 = (2 * i + 2 > 31) ? 31 : 2 * i + 2;
        bf16x8 aF[4], bF[2];
        // p1: stage b1.A <- Tb; read b0/nh0
        SAh(B1, 0, Tb); SAh(B1, 1, Tb);
        PH_START(0, 0, aF, bF);
        __builtin_amdgcn_s_barrier();
        PH_END(0, 0, aF, bF);
        __builtin_amdgcn_s_barrier();
        // p2: stage b1.B <- Tb; read b0/nh1; vmcnt(0) -> b1 fully landed
        SBh(B1, 0, Tb); SBh(B1, 1, Tb);
        PH_START(0, 1, aF, bF);
        __builtin_amdgcn_s_barrier();
        PH_END(0, 1, aF, bF);
        asm volatile("s_waitcnt vmcnt(0)" ::: "memory");
        __builtin_amdgcn_s_barrier();
        // p3: stage b0.A <- Ta2; read b1/nh0
        SAh(0, 0, Ta2); SAh(0, 1, Ta2);
        PH_START(B1, 0, aF, bF);
        __builtin_amdgcn_s_barrier();
        PH_END(B1, 0, aF, bF);
        __builtin_amdgcn_s_barrier();
        // p4: stage b0.B <- Ta2; read b1/nh1; vmcnt(0) -> b0 fully landed
        SBh(0, 0, Ta2); SBh(0, 1, Ta2);
        PH_START(B1, 1, aF, bF);
        __builtin_amdgcn_s_barrier();
        PH_END(B1, 1, aF, bF);
        asm volatile("s_waitcnt vmcnt(0)" ::: "memory");
        __builtin_amdgcn_s_barrier();
    }

    // ---- epilogue: lane owns cols colb0+nh*32+{0,1}; rows orow0+m*16+q ----
    int orow0 = bm * 256 + wr * 64 + g * 4;
    int colb0 = bn * 256 + wc * 64 + c * 2;
    if (!isKV || bn < 8) {
        ushort_t* o0 = (ushort_t*)ar.out0;
#pragma unroll
        for (int nh = 0; nh < 2; nh++) {
            int colb = colb0 + nh * 32;
            float2 bv = *(const float2*)(ar.bias0 + colb);
#pragma unroll
            for (int m = 0; m < 4; m++)
#pragma unroll
                for (int q = 0; q < 4; q++) {
                    uint_t pk = cvt_pk_bf16(acc[m][nh * 2][q] + bv.x,
                                            acc[m][nh * 2 + 1][q] + bv.y);
                    *(uint_t*)(o0 + (size_t)(orow0 + m * 16 + q) * 2048 + colb) = pk;
                }
        }
    } else {
        // V -> vt tile-major [b,h,t][d=128][kv=64] (row stride 64 ushorts)
        ushort_t* o1 = (ushort_t*)ar.out1;
#pragma unroll
        for (int nh = 0; nh < 2; nh++)
#pragma unroll
            for (int np = 0; np < 2; np++) {
                int col2 = colb0 + nh * 32 + np - 2048;
                int h = col2 >> 7, d = col2 & 127;
                float bvs = ar.bias1[col2];
#pragma unroll
                for (int m = 0; m < 4; m++) {
                    int r = orow0 + m * 16;
                    int bb = r >> 9;
                    int kvg = kvoff + (r & 511);
                    int t = kvg >> 6, ki = kvg & 63;
                    uint2 wv;
                    wv.x = cvt_pk_bf16(acc[m][nh * 2 + np][0] + bvs, acc[m][nh * 2 + np][1] + bvs);
                    wv.y = cvt_pk_bf16(acc[m][nh * 2 + np][2] + bvs, acc[m][nh * 2 + np][3] + bvs);
                    *(uint2*)(o1 + (size_t)((bb * 16 + h) * 16 + t) * 8192 + d * 64 + ki) = wv;
                }
            }
    }
}

// ======== 8-phase 128x256x(BK=64) bf16 NT GEMM (out-proj), 512 thr, 96KB LDS, fp32 out ========
__global__ __launch_bounds__(512, 2) void k_g128(G8 p0) {
    extern __shared__ __align__(16) char sm[];
    int tid = threadIdx.x, lane = tid & 63, w = tid >> 6;
    int c = lane & 15, g = lane >> 4;
    int wr = w >> 2, wc = w & 3;

    int flat = blockIdx.x;
    int re = (flat & 7) * 32 + (flat >> 3);
    int bm = re & 31, bn = re >> 5;
    G8 ar = p0;

    int l3 = lane >> 3;
    int swz = ((lane & 7) ^ l3) << 4;
    int wj0 = 2 * w, wj1 = 2 * w + 1;
    int LB0 = wj0 * 8 + l3;
    int LB1 = wj1 * 8 + l3;
    int RB0 = (LB0 >> 5) * 64 + (LB0 & 15) * 2 + ((LB0 >> 4) & 1);
    int RB1 = (LB1 >> 5) * 64 + (LB1 & 15) * 2 + ((LB1 >> 4) & 1);
    const char* sA  = (const char*)ar.A + (size_t)(bm * 128 + w * 8 + l3) * 4096 + swz;
    const char* sB0 = (const char*)ar.B + (size_t)(bn * 256 + RB0) * 4096 + swz;
    const char* sB1 = (const char*)ar.B + (size_t)(bn * 256 + RB1) * 4096 + swz;
    char* dA  = sm + w * 1024;
    char* dB0 = sm + 16384 + wj0 * 1024;
    char* dB1 = sm + 16384 + wj1 * 1024;

    auto SA = [&](int buf, int half, int t) {
        gload_lds16(sA + (size_t)half * 262144 + t * 128, dA + buf + half * 8192);
    };
    auto SB = [&](int buf, int half, int t) {
        gload_lds16(sB0 + (size_t)half * 131072 + t * 128, dB0 + buf + half * 16384);
        gload_lds16(sB1 + (size_t)half * 131072 + t * 128, dB1 + buf + half * 16384);
    };

    int bKS0 = (g << 4) ^ ((c & 7) << 4);
    int bKS1 = (64 | (g << 4)) ^ ((c & 7) << 4);
    int aoffL = wr * 8192 + c * 128;
    int boffL = 16384 + wc * 4096 + c * 128;

    f32x4 acc[4][4];
#pragma unroll
    for (int m = 0; m < 4; m++)
#pragma unroll
        for (int n = 0; n < 4; n++) acc[m][n] = (f32x4){0.f, 0.f, 0.f, 0.f};

    bf16x8 aF[2][2], bF0[2][2], bF1[2][2];

    auto RA = [&](int buf, int mhp) {
#pragma unroll
        for (int m = 0; m < 2; m++) {
            aF[m][0] = *(const bf16x8*)(sm + buf + aoffL + (mhp * 2 + m) * 2048 + bKS0);
            aF[m][1] = *(const bf16x8*)(sm + buf + aoffL + (mhp * 2 + m) * 2048 + bKS1);
        }
    };
    auto RB = [&](int buf, int nh, bf16x8 (&bF)[2][2]) {
#pragma unroll
        for (int n = 0; n < 2; n++) {
            bF[n][0] = *(const bf16x8*)(sm + buf + boffL + nh * 16384 + n * 2048 + bKS0);
            bF[n][1] = *(const bf16x8*)(sm + buf + boffL + nh * 16384 + n * 2048 + bKS1);
        }
    };
    auto MF = [&](int mhp, int nh, bf16x8 (&bF)[2][2]) {
        __builtin_amdgcn_s_setprio(1);
#pragma unroll
        for (int m = 0; m < 2; m++)
#pragma unroll
            for (int n = 0; n < 2; n++)
#pragma unroll
                for (int ks = 0; ks < 2; ks++)
                    acc[mhp * 2 + m][nh * 2 + n] = __builtin_amdgcn_mfma_f32_16x16x32_bf16(
                        aF[m][ks], bF[n][ks], acc[mhp * 2 + m][nh * 2 + n], 0, 0, 0);
        __builtin_amdgcn_s_setprio(0);
    };

    const int B1 = 49152;
    SA(0, 0, 0); SA(0, 1, 0); SB(0, 0, 0); SB(0, 1, 0);
    SA(B1, 0, 1);
    asm volatile("s_waitcnt vmcnt(1)" ::: "memory");
    __builtin_amdgcn_s_barrier();

#pragma unroll 1
    for (int i = 0; i < 16; ++i) {
        int Tb  = 2 * i + 1;
        int Ta2 = (2 * i + 2 > 31) ? 31 : 2 * i + 2;
        int Tb2 = (2 * i + 3 > 31) ? 31 : 2 * i + 3;
        // p1
        RA(0, 0); RB(0, 0, bF0);
        SA(B1, 1, Tb);
        __builtin_amdgcn_s_barrier();
        MF(0, 0, bF0);
        __builtin_amdgcn_s_barrier();
        // p2
        RB(0, 1, bF1);
        SB(B1, 0, Tb);
        __builtin_amdgcn_s_barrier();
        MF(0, 1, bF1);
        __builtin_amdgcn_s_barrier();
        // p3
        RA(0, 1);
        SB(B1, 1, Tb);
        __builtin_amdgcn_s_barrier();
        MF(1, 0, bF0);
        __builtin_amdgcn_s_barrier();
        // p4
        SA(0, 0, Ta2);
        __builtin_amdgcn_s_barrier();
        MF(1, 1, bF1);
        asm volatile("s_waitcnt vmcnt(3)" ::: "memory");
        __builtin_amdgcn_s_barrier();
        // p5
        RA(B1, 0); RB(B1, 0, bF0);
        SA(0, 1, Ta2);
        __builtin_amdgcn_s_barrier();
        MF(0, 0, bF0);
        asm volatile("s_waitcnt vmcnt(2)" ::: "memory");
        __builtin_amdgcn_s_barrier();
        // p6
        RB(B1, 1, bF1);
        SB(0, 0, Ta2);
        __builtin_amdgcn_s_barrier();
        MF(0, 1, bF1);
        __builtin_amdgcn_s_barrier();
        // p7
        RA(B1, 1);
        SB(0, 1, Ta2);
        __builtin_amdgcn_s_barrier();
        MF(1, 0, bF0);
        __builtin_amdgcn_s_barrier();
        // p8
        SA(B1, 0, Tb2);
        __builtin_amdgcn_s_barrier();
        MF(1, 1, bF1);
        asm volatile("s_waitcnt vmcnt(1)" ::: "memory");
        __builtin_amdgcn_s_barrier();
    }

    int orow0 = bm * 128 + wr * 64 + g * 4;
    int colb0 = bn * 256 + wc * 64 + c * 2;
    float* o0 = (float*)ar.out0;
#pragma unroll
    for (int nh = 0; nh < 2; nh++) {
        int colb = colb0 + nh * 32;
        float2 bv = *(const float2*)(ar.bias0 + colb);
#pragma unroll
        for (int m = 0; m < 4; m++)
#pragma unroll
            for (int q = 0; q < 4; q++) {
                float2 st = {acc[m][nh * 2][q] + bv.x, acc[m][nh * 2 + 1][q] + bv.y};
                *(float2*)(o0 + (size_t)(orow0 + m * 16 + q) * 2048 + colb) = st;
            }
    }
}

// ---------------- merged RMSNorm + RoPE: bf16 row-major in -> packed [b,h,s,128] bf16 out ----------------
struct RR { const ushort_t* in; const float* gain; const float* freqs; ushort_t* out; int lgS; float scale; };
__global__ __launch_bounds__(256) void k_rr(RR a0, RR a1, RR a2) {
    int bid = blockIdx.x;
    RR a; int row;
    if (bid < 4096) { a = a0; row = bid; }
    else if (bid < 5120) { a = a1; row = bid - 4096; }
    else { a = a2; row = bid - 5120; }
    int S = 1 << a.lgS;
    int s = row & (S - 1);
    int b = row >> a.lgS;
    int tid = threadIdx.x;
    uint4 v = *(const uint4*)(a.in + (size_t)row * 2048 + tid * 8);
    ushort_t us[8];
    us[0] = (ushort_t)(v.x & 0xffff); us[1] = (ushort_t)(v.x >> 16);
    us[2] = (ushort_t)(v.y & 0xffff); us[3] = (ushort_t)(v.y >> 16);
    us[4] = (ushort_t)(v.z & 0xffff); us[5] = (ushort_t)(v.z >> 16);
    us[6] = (ushort_t)(v.w & 0xffff); us[7] = (ushort_t)(v.w >> 16);
    float y[8];
#pragma unroll
    for (int j = 0; j < 8; j++) y[j] = b2f(us[j]);
    float ss = 0.f;
#pragma unroll
    for (int j = 0; j < 8; j++) ss += y[j] * y[j];
#pragma unroll
    for (int off = 32; off > 0; off >>= 1) ss += __shfl_xor(ss, off, 64);
    __shared__ float red[4];
    int lane = tid & 63, wid = tid >> 6;
    if (lane == 0) red[wid] = ss;
    __syncthreads();
    float tot = red[0] + red[1] + red[2] + red[3];
    float inv = rsqrtf(tot * (1.0f / DIM) + 1e-6f);
    const float* gp = a.gain + tid * 8;
    float4 g0 = *(const float4*)gp;
    float4 g1 = *(const float4*)(gp + 4);
    float gg[8] = {g0.x, g0.y, g0.z, g0.w, g1.x, g1.y, g1.z, g1.w};
    int p0 = (tid * 8 & 127) >> 1;
    const float* fq = a.freqs + ((size_t)s * 64 + p0) * 2;
    uint_t ow[4];
#pragma unroll
    for (int j = 0; j < 4; j++) {
        float fr = fq[j * 2 + 0], fi = fq[j * 2 + 1];
        float xr = y[2 * j] * inv * gg[2 * j];
        float xi = y[2 * j + 1] * inv * gg[2 * j + 1];
        float o0 = (xr * fr - xi * fi) * a.scale;
        float o1 = (xr * fi + xi * fr) * a.scale;
        ow[j] = (uint_t)f2b(o0) | ((uint_t)f2b(o1) << 16);
    }
    int h = tid >> 4;
    ushort_t* dst = a.out + ((size_t)((b * 16 + h) * S + s)) * 128 + (tid & 15) * 8;
    *(uint4*)dst = make_uint4(ow[0], ow[1], ow[2], ow[3]);
}

// ---------------- flash attention: 8 waves, 128 q/block, dbuf K/V, packed inputs ----------------
__global__ __launch_bounds__(512, 4) void k_attn(const ushort_t* __restrict__ Q,
                                                 const ushort_t* __restrict__ Kc,
                                                 const ushort_t* __restrict__ Kr,
                                                 const ushort_t* __restrict__ Vt,
                                                 ushort_t* __restrict__ O) {
    __shared__ __align__(16) char sm[65536];
    int tid = threadIdx.x, lane = tid & 63, w = tid >> 6;
    int c = lane & 15, g = lane >> 4;

    int bid = blockIdx.x;
    int xcd = bid & 7, idx = bid >> 3;
    int combo = idx & 3, qt = idx >> 2;
    int b = combo >> 1, h = xcd * 2 + (combo & 1);
    int bh = b * 16 + h;

    const ushort_t* qg = Q + ((size_t)(bh * 2048 + qt * 128 + w * 16 + c)) * 128 + g * 8;
    bf16x8 aQ[4];
#pragma unroll
    for (int ks = 0; ks < 4; ks++) aQ[ks] = *(const bf16x8*)(qg + ks * 32);

    int kbase[4], vbase[8];
#pragma unroll
    for (int n = 0; n < 4; n++) {
        int row = ((n >> 1) << 5) + ((c >> 2) << 3) + ((n & 1) << 2) + (c & 3);
        int sw = (row & 3) | (((row >> 3) & 3) << 2);
        kbase[n] = row * 256 + ((g ^ sw) << 4);
    }
#pragma unroll
    for (int dt = 0; dt < 8; dt++) {
        int vrow = dt * 16 + c;
        vbase[dt] = vrow * 128 + ((g ^ (vrow & 7)) << 4);
    }

    int swk = (lane >> 4) | ((w & 3) << 2);
    int klo = (8 * w + (lane >> 4)) * 256 + (((lane & 15) ^ swk) << 4);
    int vlo = (16 * w + (lane >> 3)) * 128 + (((lane & 7) ^ (lane >> 3)) << 4);
    int dst0 = w * 2048;

    const char* kcb = (const char*)Kc + (size_t)bh * 131072;
    const char* krb = (const char*)Kr + (size_t)bh * 131072;
    const char* vtb = (const char*)Vt + (size_t)bh * 262144;

    float mr = -1e30f, lr = 0.f;
    f32x4 o[8];
#pragma unroll
    for (int d = 0; d < 8; d++) o[d] = (f32x4){0, 0, 0, 0};

    auto STAGE = [&](int DB, int t) {
        const char* kg = (t < 8) ? kcb + t * 16384 : krb + (t - 8) * 16384;
        const char* vg = vtb + t * 16384;
        gload_lds16(kg + klo, sm + DB + dst0);
        gload_lds16(kg + klo + 1024, sm + DB + dst0 + 1024);
        gload_lds16(vg + vlo, sm + DB + 16384 + dst0);
        gload_lds16(vg + vlo + 1024, sm + DB + 16384 + dst0 + 1024);
    };

    auto TILE = [&](int DB) {
        f32x4 sT[4];
#pragma unroll
        for (int n = 0; n < 4; n++) sT[n] = (f32x4){0, 0, 0, 0};
#pragma unroll
        for (int n = 0; n < 4; n++)
#pragma unroll
            for (int ks = 0; ks < 4; ks++) {
                bf16x8 aK = *(const bf16x8*)(sm + DB + (kbase[n] ^ (ks << 6)));
                sT[n] = __builtin_amdgcn_mfma_f32_16x16x32_bf16(aK, aQ[ks], sT[n], 0, 0, 0);
            }
        float mloc = sT[0][0];
#pragma unroll
        for (int n = 0; n < 4; n++)
#pragma unroll
            for (int r = 0; r < 4; r++) mloc = fmaxf(mloc, sT[n][r]);
        if (!__all(mloc - mr <= 8.0f)) {
            float mx = fmaxf(mloc, __shfl_xor(mloc, 16, 64));
            mx = fmaxf(mx, __shfl_xor(mx, 32, 64));
            float mn = fmaxf(mr, mx);
            float al = exp2f(mr - mn);
            mr = mn;
            lr *= al;
#pragma unroll
            for (int d = 0; d < 8; d++) o[d] *= al;
        }
        float p[4][4];
        float ps = 0.f;
#pragma unroll
        for (int n = 0; n < 4; n++)
#pragma unroll
            for (int r = 0; r < 4; r++) {
                p[n][r] = exp2f(sT[n][r] - mr);
                ps += p[n][r];
            }
        lr += ps;
#pragma unroll
        for (int kk = 0; kk < 2; kk++) {
            union { uint_t u[4]; bf16x8 v; } bP;
            bP.u[0] = cvt_pk_bf16(p[2 * kk][0], p[2 * kk][1]);
            bP.u[1] = cvt_pk_bf16(p[2 * kk][2], p[2 * kk][3]);
            bP.u[2] = cvt_pk_bf16(p[2 * kk + 1][0], p[2 * kk + 1][1]);
            bP.u[3] = cvt_pk_bf16(p[2 * kk + 1][2], p[2 * kk + 1][3]);
#pragma unroll
            for (int dt = 0; dt < 8; dt++) {
                bf16x8 aV = *(const bf16x8*)(sm + DB + 16384 + (vbase[dt] ^ (kk << 6)));
                o[dt] = __builtin_amdgcn_mfma_f32_16x16x32_bf16(aV, bP.v, o[dt], 0, 0, 0);
            }
        }
    };

    STAGE(0, 0);
    __syncthreads();
#pragma unroll 1
    for (int t = 0; t < 16; t += 2) {
        STAGE(32768, t + 1);
        TILE(0);
        __syncthreads();
        if (t < 14) STAGE(0, t + 2);
        TILE(32768);
        __syncthreads();
    }

    lr += __shfl_xor(lr, 16, 64);
    lr += __shfl_xor(lr, 32, 64);
    float inv = 1.0f / lr;
    ushort_t* lO = (ushort_t*)sm;
#pragma unroll
    for (int dt = 0; dt < 8; dt++) {
        uint2 wv;
        wv.x = (uint_t)f2b(o[dt][0] * inv) | ((uint_t)f2b(o[dt][1] * inv) << 16);
        wv.y = (uint_t)f2b(o[dt][2] * inv) | ((uint_t)f2b(o[dt][3] * inv) << 16);
        *(uint2*)(lO + (w * 16 + c) * 136 + dt * 16 + g * 4) = wv;
    }
    __syncthreads();
    int row = tid >> 2, c8 = tid & 3;
    const ushort_t* src = lO + row * 136 + c8 * 32;
    ushort_t* dst = O + (size_t)(b * 2048 + qt * 128 + row) * 2048 + h * 128 + c8 * 32;
#pragma unroll
    for (int k = 0; k < 4; k++) *(uint4*)(dst + k * 8) = *(const uint4*)(src + k * 8);
}

extern "C" void kernel_launch(void* const* d_in, const int* in_sizes, int n_in,
                              void* d_out, int out_size, void* d_ws, size_t ws_size,
                              hipStream_t stream) {
    const float* x   = (const float*)d_in[0];
    const float* cam = (const float*)d_in[1];
    const float* ren = (const float*)d_in[2];
    const float* fx  = (const float*)d_in[3];
    const float* fc  = (const float*)d_in[4];
    const float* fr  = (const float*)d_in[5];
    const float* wq  = (const float*)d_in[6];
    const float* bq  = (const float*)d_in[7];
    const float* wk  = (const float*)d_in[8];
    const float* bk  = (const float*)d_in[9];
    const float* wv  = (const float*)d_in[10];
    const float* bv  = (const float*)d_in[11];
    const float* wkr = (const float*)d_in[12];
    const float* bkr = (const float*)d_in[13];
    const float* wvr = (const float*)d_in[14];
    const float* bvr = (const float*)d_in[15];
    const float* wo  = (const float*)d_in[16];
    const float* bo  = (const float*)d_in[17];
    const float* gq  = (const float*)d_in[18];
    const float* gk  = (const float*)d_in[19];

    char* ws = (char*)d_ws;
    ushort_t* wq_b     = (ushort_t*)(ws + 0);
    ushort_t* wk_b     = (ushort_t*)(ws + 8388608);    // wk||wv contiguous (N=4096)
    ushort_t* wkr_b    = (ushort_t*)(ws + 25165824);   // wkr||wvr contiguous
    ushort_t* wo_b     = (ushort_t*)(ws + 41943040);
    ushort_t* xb       = (ushort_t*)(ws + 50331648);   // reused by attn_bf later
    ushort_t* camb     = (ushort_t*)(ws + 67108864);
    ushort_t* renb     = (ushort_t*)(ws + 71303168);
    ushort_t* kcam_lin = (ushort_t*)(ws + 75497472);   // bf16 [1024][2048]
    ushort_t* kren_lin = (ushort_t*)(ws + 79691776);
    ushort_t* vt       = (ushort_t*)(ws + 83886080);   // tile-major V, 8MB
    ushort_t* q_bf     = (ushort_t*)(ws + 92274688);   // packed [b,h,2048,128]
    ushort_t* kcam_bf  = (ushort_t*)(ws + 109051904);  // packed [b,h,512,128]
    ushort_t* kren_bf  = (ushort_t*)(ws + 113246208);
    ushort_t* attn_bf  = (ushort_t*)(ws + 50331648);   // overlays dead xb
    ushort_t* q_lin    = (ushort_t*)d_out;             // d_out doubles as bf16 Q-proj scratch

    hipFuncSetAttribute(reinterpret_cast<const void*>(&k_g256),
                        hipFuncAttributeMaxDynamicSharedMemorySize, 131072);
    hipFuncSetAttribute(reinterpret_cast<const void*>(&k_g128),
                        hipFuncAttributeMaxDynamicSharedMemorySize, 98304);

    // all fp32 -> bf16 converts (weights + activations) in one dispatch
    ushort_t* wv_b  = wk_b + 4194304;
    ushort_t* wvr_b = wkr_b + 4194304;
    Cvt9 c9;
    c9.s[0] = wq;  c9.d[0] = wq_b;  c9.n[0] = 4194304;
    c9.s[1] = wk;  c9.d[1] = wk_b;  c9.n[1] = 4194304;
    c9.s[2] = wv;  c9.d[2] = wv_b;  c9.n[2] = 4194304;
    c9.s[3] = wkr; c9.d[3] = wkr_b; c9.n[3] = 4194304;
    c9.s[4] = wvr; c9.d[4] = wvr_b; c9.n[4] = 4194304;
    c9.s[5] = wo;  c9.d[5] = wo_b;  c9.n[5] = 4194304;
    c9.s[6] = x;   c9.d[6] = xb;    c9.n[6] = 8388608;
    c9.s[7] = cam; c9.d[7] = camb;  c9.n[7] = 2097152;
    c9.s[8] = ren; c9.d[8] = renb;  c9.n[8] = 2097152;
    k_cvt9<<<dim3(2048, 9), 256, 0, stream>>>(c9);

    // merged Q + K/V projections (4-phase 256^2, 1024 thr, 256 blocks); V lands in vt
    G8 qa{xb, wq_b, bq, nullptr, (void*)q_lin, nullptr};
    G8 kva0{camb, wk_b, bk, bv, (void*)kcam_lin, (void*)vt};
    G8 kva1{renb, wkr_b, bkr, bvr, (void*)kren_lin, (void*)vt};
    k_g256<<<dim3(256, 1, 1), 1024, 131072, stream>>>(qa, kva0, kva1);

    // merged RMSNorm+RoPE (Q folds (1/sqrt(HD))*log2(e)); outputs packed per-head
    RR r0{q_lin, gq, fx, q_bf, 11, 0.08838834764831845f * 1.4426950408889634f};
    RR r1{kcam_lin, gk, fc, kcam_bf, 9, 1.0f};
    RR r2{kren_lin, gk, fr, kren_bf, 9, 1.0f};
    k_rr<<<dim3(6144, 1, 1), 256, 0, stream>>>(r0, r1, r2);

    // flash attention (flat 512, XCD-pinned, contiguous staging)
    k_attn<<<dim3(512, 1, 1), 512, 0, stream>>>(q_bf, kcam_bf, kren_bf, vt, attn_bf);

    // output projection -> d_out (fp32), 8-phase 128x256, 256 blocks
    G8 oa{attn_bf, wo_b, bo, nullptr, d_out, nullptr};
    k_g128<<<dim3(256, 1, 1), 512, 98304, stream>>>(oa);
}

// Round 13
// 204.973 us; speedup vs baseline: 1.0310x; 1.0310x over previous
//
#include <hip/hip_runtime.h>

typedef short bf16x8 __attribute__((ext_vector_type(8)));
typedef float f32x4 __attribute__((ext_vector_type(4)));
typedef unsigned short ushort_t;
typedef unsigned int uint_t;

#define DIM 2048
#define NH 16
#define HD 128

__device__ __forceinline__ ushort_t f2b(float f) {
    union { float f; uint_t u; } a; a.f = f;
    uint_t u = a.u;
    return (ushort_t)((u + 0x7fffu + ((u >> 16) & 1u)) >> 16);
}

__device__ __forceinline__ float b2f(ushort_t s) {
    union { uint_t u; float f; } a; a.u = ((uint_t)s) << 16;
    return a.f;
}

__device__ __forceinline__ uint_t cvt_pk_bf16(float lo, float hi) {
    uint_t r;
    asm("v_cvt_pk_bf16_f32 %0, %1, %2" : "=v"(r) : "v"(lo), "v"(hi));
    return r;
}

__device__ __forceinline__ void gload_lds16(const void* g, void* l) {
    void* gg = const_cast<void*>(g);
    __builtin_amdgcn_global_load_lds(
        (__attribute__((address_space(1))) uint_t*)gg,
        (__attribute__((address_space(3))) uint_t*)l, 16, 0, 0);
}

// ---------------- all fp32->bf16 converts in ONE dispatch ----------------
struct Cvt9 { const float* s[9]; ushort_t* d[9]; int n[9]; };
__global__ __launch_bounds__(256) void k_cvt9(Cvt9 a) {
    int y = blockIdx.y;
    const float* in = a.s[y];
    ushort_t* out = a.d[y];
    int n = a.n[y];
    for (int idx = (blockIdx.x * 256 + threadIdx.x) * 8; idx < n; idx += 2048 * 256 * 8) {
        float4 p = *(const float4*)(in + idx);
        float4 q = *(const float4*)(in + idx + 4);
        uint4 o;
        o.x = (uint_t)f2b(p.x) | ((uint_t)f2b(p.y) << 16);
        o.y = (uint_t)f2b(p.z) | ((uint_t)f2b(p.w) << 16);
        o.z = (uint_t)f2b(q.x) | ((uint_t)f2b(q.y) << 16);
        o.w = (uint_t)f2b(q.z) | ((uint_t)f2b(q.w) << 16);
        *(uint4*)(out + idx) = o;
    }
}

struct G8 {
    const ushort_t* A;
    const ushort_t* B;
    const float* bias0;
    const float* bias1;
    void* out0;
    void* out1;
};

// ======== 8-phase 256x256x(BK=64) bf16 NT GEMM (merged QKV), 512 thr, 128KB LDS ========
// B rows staged with within-32 permutation rho(j)=(j&15)*2+(j>>4) so lane c owns
// output cols {c*2, c*2+1} per (wc,nh) window -> packed uint stores.
__global__ __launch_bounds__(512, 2) void k_g256(G8 p0, G8 p1, G8 p2) {
    extern __shared__ __align__(16) char sm[];
    int tid = threadIdx.x, lane = tid & 63, w = tid >> 6;
    int c = lane & 15, g = lane >> 4;
    int wr = w >> 2, wc = w & 3;

    int flat = blockIdx.x;
    G8 ar;
    int bm, bn, isKV = 0, kvoff = 0;
    {
        int re = (flat & 7) * 32 + (flat >> 3);
        if (re < 128) { ar = p0; bm = re & 15; bn = re >> 4; }
        else {
            int r2 = re - 128;
            int z = r2 >> 6; r2 &= 63;
            ar = z ? p2 : p1;
            bm = r2 & 3; bn = r2 >> 2;
            isKV = 1; kvoff = z ? 512 : 0;
        }
    }

    int wj0 = 2 * w, wj1 = 2 * w + 1;
    int l3 = lane >> 3;
    int swz = ((lane & 7) ^ l3) << 4;
    int RA0 = (wj0 >> 3) * 128 + (wj0 & 7) * 8 + l3;
    int RA1 = (wj1 >> 3) * 128 + (wj1 & 7) * 8 + l3;
    // B source rows: rho-permuted within each 32-row window (packed-epilogue map)
    int LB0 = wj0 * 8 + l3;
    int LB1 = wj1 * 8 + l3;
    int RB0 = (LB0 >> 5) * 64 + (LB0 & 15) * 2 + ((LB0 >> 4) & 1);
    int RB1 = (LB1 >> 5) * 64 + (LB1 & 15) * 2 + ((LB1 >> 4) & 1);
    const char* sA0 = (const char*)ar.A + (size_t)(bm * 256 + RA0) * 4096 + swz;
    const char* sA1 = (const char*)ar.A + (size_t)(bm * 256 + RA1) * 4096 + swz;
    const char* sB0 = (const char*)ar.B + (size_t)(bn * 256 + RB0) * 4096 + swz;
    const char* sB1 = (const char*)ar.B + (size_t)(bn * 256 + RB1) * 4096 + swz;
    char* dA0 = sm + wj0 * 1024;
    char* dA1 = sm + wj1 * 1024;
    char* dB0 = sm + 32768 + wj0 * 1024;
    char* dB1 = sm + 32768 + wj1 * 1024;

    auto SA = [&](int buf, int half, int t) {
        gload_lds16(sA0 + (size_t)half * 262144 + t * 128, dA0 + buf + half * 16384);
        gload_lds16(sA1 + (size_t)half * 262144 + t * 128, dA1 + buf + half * 16384);
    };
    auto SB = [&](int buf, int half, int t) {
        gload_lds16(sB0 + (size_t)half * 131072 + t * 128, dB0 + buf + half * 16384);
        gload_lds16(sB1 + (size_t)half * 131072 + t * 128, dB1 + buf + half * 16384);
    };

    int bKS0 = (g << 4) ^ ((c & 7) << 4);
    int bKS1 = (64 | (g << 4)) ^ ((c & 7) << 4);
    int aoffL = wr * 8192 + c * 128;
    int boffL = 32768 + wc * 4096 + c * 128;

    f32x4 acc[8][4];
#pragma unroll
    for (int m = 0; m < 8; m++)
#pragma unroll
        for (int n = 0; n < 4; n++) acc[m][n] = (f32x4){0.f, 0.f, 0.f, 0.f};

    bf16x8 aF[4][2], bF0[2][2], bF1[2][2];

    auto RA = [&](int buf, int mh) {
#pragma unroll
        for (int m = 0; m < 4; m++) {
            aF[m][0] = *(const bf16x8*)(sm + buf + mh * 16384 + aoffL + m * 2048 + bKS0);
            aF[m][1] = *(const bf16x8*)(sm + buf + mh * 16384 + aoffL + m * 2048 + bKS1);
        }
    };
    auto RB = [&](int buf, int nh, bf16x8 (&bF)[2][2]) {
#pragma unroll
        for (int n = 0; n < 2; n++) {
            bF[n][0] = *(const bf16x8*)(sm + buf + boffL + nh * 16384 + n * 2048 + bKS0);
            bF[n][1] = *(const bf16x8*)(sm + buf + boffL + nh * 16384 + n * 2048 + bKS1);
        }
    };
    auto MF = [&](int mh, int nh, bf16x8 (&bF)[2][2]) {
        __builtin_amdgcn_s_setprio(1);
#pragma unroll
        for (int m = 0; m < 4; m++)
#pragma unroll
            for (int n = 0; n < 2; n++)
#pragma unroll
                for (int ks = 0; ks < 2; ks++)
                    acc[mh * 4 + m][nh * 2 + n] = __builtin_amdgcn_mfma_f32_16x16x32_bf16(
                        aF[m][ks], bF[n][ks], acc[mh * 4 + m][nh * 2 + n], 0, 0, 0);
        __builtin_amdgcn_s_setprio(0);
    };

    SA(0, 0, 0); SB(0, 0, 0); SA(0, 1, 0); SB(0, 1, 0);
    SA(65536, 0, 1); SB(65536, 0, 1);
    asm volatile("s_waitcnt vmcnt(8)" ::: "memory");
    __builtin_amdgcn_s_barrier();

#pragma unroll 1
    for (int i = 0; i < 16; ++i) {
        int Tb  = 2 * i + 1;
        int Ta2 = (2 * i + 2 > 31) ? 31 : 2 * i + 2;
        int Tb2 = (2 * i + 3 > 31) ? 31 : 2 * i + 3;
        // p1
        RA(0, 0); RB(0, 0, bF0);
        SA(65536, 1, Tb);
        __builtin_amdgcn_s_barrier();
        MF(0, 0, bF0);
        asm volatile("s_waitcnt vmcnt(6)" ::: "memory");
        __builtin_amdgcn_s_barrier();
        // p2
        RB(0, 1, bF1);
        SB(65536, 1, Tb);
        __builtin_amdgcn_s_barrier();
        MF(0, 1, bF1);
        __builtin_amdgcn_s_barrier();
        // p3
        RA(0, 1);
        SA(0, 0, Ta2);
        __builtin_amdgcn_s_barrier();
        MF(1, 0, bF0);
        __builtin_amdgcn_s_barrier();
        // p4
        SB(0, 0, Ta2);
        __builtin_amdgcn_s_barrier();
        MF(1, 1, bF1);
        asm volatile("s_waitcnt vmcnt(8)" ::: "memory");
        __builtin_amdgcn_s_barrier();
        // p5
        RA(65536, 0); RB(65536, 0, bF0);
        SA(0, 1, Ta2);
        __builtin_amdgcn_s_barrier();
        MF(0, 0, bF0);
        asm volatile("s_waitcnt vmcnt(6)" ::: "memory");
        __builtin_amdgcn_s_barrier();
        // p6
        RB(65536, 1, bF1);
        SB(0, 1, Ta2);
        __builtin_amdgcn_s_barrier();
        MF(0, 1, bF1);
        __builtin_amdgcn_s_barrier();
        // p7
        RA(65536, 1);
        SA(65536, 0, Tb2);
        __builtin_amdgcn_s_barrier();
        MF(1, 0, bF0);
        __builtin_amdgcn_s_barrier();
        // p8
        SB(65536, 0, Tb2);
        __builtin_amdgcn_s_barrier();
        MF(1, 1, bF1);
        asm volatile("s_waitcnt vmcnt(8)" ::: "memory");
        __builtin_amdgcn_s_barrier();
    }

    // epilogue: lane owns cols colb0+nh*32+{0,1}; rows orow0+m*16+q
    int orow0 = bm * 256 + wr * 128 + g * 4;
    int colb0 = bn * 256 + wc * 64 + c * 2;
    if (!isKV || bn < 8) {
        // Q or K: bf16 row-major ld 2048; packed uint stores (64B/16-lane group)
        ushort_t* o0 = (ushort_t*)ar.out0;
#pragma unroll
        for (int nh = 0; nh < 2; nh++) {
            int colb = colb0 + nh * 32;
            float2 bv = *(const float2*)(ar.bias0 + colb);
#pragma unroll
            for (int m = 0; m < 8; m++)
#pragma unroll
                for (int q = 0; q < 4; q++) {
                    uint_t pk = cvt_pk_bf16(acc[m][nh * 2][q] + bv.x,
                                            acc[m][nh * 2 + 1][q] + bv.y);
                    *(uint_t*)(o0 + (size_t)(orow0 + m * 16 + q) * 2048 + colb) = pk;
                }
        }
    } else {
        // V -> vt tile-major [b,h,t][d=128][kv=64] (row stride 64 ushorts)
        ushort_t* o1 = (ushort_t*)ar.out1;
#pragma unroll
        for (int nh = 0; nh < 2; nh++)
#pragma unroll
            for (int np = 0; np < 2; np++) {
                int col2 = colb0 + nh * 32 + np - 2048;
                int h = col2 >> 7, d = col2 & 127;
                float bvs = ar.bias1[col2];
#pragma unroll
                for (int m = 0; m < 8; m++) {
                    int r = orow0 + m * 16;
                    int bb = r >> 9;
                    int kvg = kvoff + (r & 511);
                    int t = kvg >> 6, ki = kvg & 63;
                    uint2 wv;
                    wv.x = cvt_pk_bf16(acc[m][nh * 2 + np][0] + bvs, acc[m][nh * 2 + np][1] + bvs);
                    wv.y = cvt_pk_bf16(acc[m][nh * 2 + np][2] + bvs, acc[m][nh * 2 + np][3] + bvs);
                    *(uint2*)(o1 + (size_t)((bb * 16 + h) * 16 + t) * 8192 + d * 64 + ki) = wv;
                }
            }
    }
}

// ======== 8-phase 128x256x(BK=64) bf16 NT GEMM (out-proj), 512 thr, 96KB LDS, fp32 out ========
__global__ __launch_bounds__(512, 2) void k_g128(G8 p0) {
    extern __shared__ __align__(16) char sm[];
    int tid = threadIdx.x, lane = tid & 63, w = tid >> 6;
    int c = lane & 15, g = lane >> 4;
    int wr = w >> 2, wc = w & 3;

    int flat = blockIdx.x;
    int re = (flat & 7) * 32 + (flat >> 3);
    int bm = re & 31, bn = re >> 5;   // XCD owns one B panel (1MB), streams A
    G8 ar = p0;

    int l3 = lane >> 3;
    int swz = ((lane & 7) ^ l3) << 4;
    int wj0 = 2 * w, wj1 = 2 * w + 1;
    int LB0 = wj0 * 8 + l3;
    int LB1 = wj1 * 8 + l3;
    int RB0 = (LB0 >> 5) * 64 + (LB0 & 15) * 2 + ((LB0 >> 4) & 1);
    int RB1 = (LB1 >> 5) * 64 + (LB1 & 15) * 2 + ((LB1 >> 4) & 1);
    const char* sA  = (const char*)ar.A + (size_t)(bm * 128 + w * 8 + l3) * 4096 + swz;
    const char* sB0 = (const char*)ar.B + (size_t)(bn * 256 + RB0) * 4096 + swz;
    const char* sB1 = (const char*)ar.B + (size_t)(bn * 256 + RB1) * 4096 + swz;
    char* dA  = sm + w * 1024;
    char* dB0 = sm + 16384 + wj0 * 1024;
    char* dB1 = sm + 16384 + wj1 * 1024;

    auto SA = [&](int buf, int half, int t) {
        gload_lds16(sA + (size_t)half * 262144 + t * 128, dA + buf + half * 8192);
    };
    auto SB = [&](int buf, int half, int t) {
        gload_lds16(sB0 + (size_t)half * 131072 + t * 128, dB0 + buf + half * 16384);
        gload_lds16(sB1 + (size_t)half * 131072 + t * 128, dB1 + buf + half * 16384);
    };

    int bKS0 = (g << 4) ^ ((c & 7) << 4);
    int bKS1 = (64 | (g << 4)) ^ ((c & 7) << 4);
    int aoffL = wr * 8192 + c * 128;
    int boffL = 16384 + wc * 4096 + c * 128;

    f32x4 acc[4][4];
#pragma unroll
    for (int m = 0; m < 4; m++)
#pragma unroll
        for (int n = 0; n < 4; n++) acc[m][n] = (f32x4){0.f, 0.f, 0.f, 0.f};

    bf16x8 aF[2][2], bF0[2][2], bF1[2][2];

    auto RA = [&](int buf, int mhp) {
#pragma unroll
        for (int m = 0; m < 2; m++) {
            aF[m][0] = *(const bf16x8*)(sm + buf + aoffL + (mhp * 2 + m) * 2048 + bKS0);
            aF[m][1] = *(const bf16x8*)(sm + buf + aoffL + (mhp * 2 + m) * 2048 + bKS1);
        }
    };
    auto RB = [&](int buf, int nh, bf16x8 (&bF)[2][2]) {
#pragma unroll
        for (int n = 0; n < 2; n++) {
            bF[n][0] = *(const bf16x8*)(sm + buf + boffL + nh * 16384 + n * 2048 + bKS0);
            bF[n][1] = *(const bf16x8*)(sm + buf + boffL + nh * 16384 + n * 2048 + bKS1);
        }
    };
    auto MF = [&](int mhp, int nh, bf16x8 (&bF)[2][2]) {
        __builtin_amdgcn_s_setprio(1);
#pragma unroll
        for (int m = 0; m < 2; m++)
#pragma unroll
            for (int n = 0; n < 2; n++)
#pragma unroll
                for (int ks = 0; ks < 2; ks++)
                    acc[mhp * 2 + m][nh * 2 + n] = __builtin_amdgcn_mfma_f32_16x16x32_bf16(
                        aF[m][ks], bF[n][ks], acc[mhp * 2 + m][nh * 2 + n], 0, 0, 0);
        __builtin_amdgcn_s_setprio(0);
    };

    const int B1 = 49152;
    SA(0, 0, 0); SA(0, 1, 0); SB(0, 0, 0); SB(0, 1, 0);
    SA(B1, 0, 1);
    asm volatile("s_waitcnt vmcnt(1)" ::: "memory");
    __builtin_amdgcn_s_barrier();

#pragma unroll 1
    for (int i = 0; i < 16; ++i) {
        int Tb  = 2 * i + 1;
        int Ta2 = (2 * i + 2 > 31) ? 31 : 2 * i + 2;
        int Tb2 = (2 * i + 3 > 31) ? 31 : 2 * i + 3;
        // p1
        RA(0, 0); RB(0, 0, bF0);
        SA(B1, 1, Tb);
        __builtin_amdgcn_s_barrier();
        MF(0, 0, bF0);
        __builtin_amdgcn_s_barrier();
        // p2
        RB(0, 1, bF1);
        SB(B1, 0, Tb);
        __builtin_amdgcn_s_barrier();
        MF(0, 1, bF1);
        __builtin_amdgcn_s_barrier();
        // p3
        RA(0, 1);
        SB(B1, 1, Tb);
        __builtin_amdgcn_s_barrier();
        MF(1, 0, bF0);
        __builtin_amdgcn_s_barrier();
        // p4
        SA(0, 0, Ta2);
        __builtin_amdgcn_s_barrier();
        MF(1, 1, bF1);
        asm volatile("s_waitcnt vmcnt(3)" ::: "memory");
        __builtin_amdgcn_s_barrier();
        // p5
        RA(B1, 0); RB(B1, 0, bF0);
        SA(0, 1, Ta2);
        __builtin_amdgcn_s_barrier();
        MF(0, 0, bF0);
        asm volatile("s_waitcnt vmcnt(2)" ::: "memory");
        __builtin_amdgcn_s_barrier();
        // p6
        RB(B1, 1, bF1);
        SB(0, 0, Ta2);
        __builtin_amdgcn_s_barrier();
        MF(0, 1, bF1);
        __builtin_amdgcn_s_barrier();
        // p7
        RA(B1, 1);
        SB(0, 1, Ta2);
        __builtin_amdgcn_s_barrier();
        MF(1, 0, bF0);
        __builtin_amdgcn_s_barrier();
        // p8
        SA(B1, 0, Tb2);
        __builtin_amdgcn_s_barrier();
        MF(1, 1, bF1);
        asm volatile("s_waitcnt vmcnt(1)" ::: "memory");
        __builtin_amdgcn_s_barrier();
    }

    // epilogue: float2 stores -> 128B full lines per 16-lane group
    int orow0 = bm * 128 + wr * 64 + g * 4;
    int colb0 = bn * 256 + wc * 64 + c * 2;
    float* o0 = (float*)ar.out0;
#pragma unroll
    for (int nh = 0; nh < 2; nh++) {
        int colb = colb0 + nh * 32;
        float2 bv = *(const float2*)(ar.bias0 + colb);
#pragma unroll
        for (int m = 0; m < 4; m++)
#pragma unroll
            for (int q = 0; q < 4; q++) {
                float2 st = {acc[m][nh * 2][q] + bv.x, acc[m][nh * 2 + 1][q] + bv.y};
                *(float2*)(o0 + (size_t)(orow0 + m * 16 + q) * 2048 + colb) = st;
            }
    }
}

// ---------------- merged RMSNorm + RoPE: bf16 row-major in -> packed [b,h,s,128] bf16 out ----------------
struct RR { const ushort_t* in; const float* gain; const float* freqs; ushort_t* out; int lgS; float scale; };
__global__ __launch_bounds__(256) void k_rr(RR a0, RR a1, RR a2) {
    int bid = blockIdx.x;
    RR a; int row;
    if (bid < 4096) { a = a0; row = bid; }
    else if (bid < 5120) { a = a1; row = bid - 4096; }
    else { a = a2; row = bid - 5120; }
    int S = 1 << a.lgS;
    int s = row & (S - 1);
    int b = row >> a.lgS;
    int tid = threadIdx.x;
    uint4 v = *(const uint4*)(a.in + (size_t)row * 2048 + tid * 8);
    ushort_t us[8];
    us[0] = (ushort_t)(v.x & 0xffff); us[1] = (ushort_t)(v.x >> 16);
    us[2] = (ushort_t)(v.y & 0xffff); us[3] = (ushort_t)(v.y >> 16);
    us[4] = (ushort_t)(v.z & 0xffff); us[5] = (ushort_t)(v.z >> 16);
    us[6] = (ushort_t)(v.w & 0xffff); us[7] = (ushort_t)(v.w >> 16);
    float y[8];
#pragma unroll
    for (int j = 0; j < 8; j++) y[j] = b2f(us[j]);
    float ss = 0.f;
#pragma unroll
    for (int j = 0; j < 8; j++) ss += y[j] * y[j];
#pragma unroll
    for (int off = 32; off > 0; off >>= 1) ss += __shfl_xor(ss, off, 64);
    __shared__ float red[4];
    int lane = tid & 63, wid = tid >> 6;
    if (lane == 0) red[wid] = ss;
    __syncthreads();
    float tot = red[0] + red[1] + red[2] + red[3];
    float inv = rsqrtf(tot * (1.0f / DIM) + 1e-6f);
    const float* gp = a.gain + tid * 8;
    float4 g0 = *(const float4*)gp;
    float4 g1 = *(const float4*)(gp + 4);
    float gg[8] = {g0.x, g0.y, g0.z, g0.w, g1.x, g1.y, g1.z, g1.w};
    int p0 = (tid * 8 & 127) >> 1;
    const float* fq = a.freqs + ((size_t)s * 64 + p0) * 2;
    uint_t ow[4];
#pragma unroll
    for (int j = 0; j < 4; j++) {
        float fr = fq[j * 2 + 0], fi = fq[j * 2 + 1];
        float xr = y[2 * j] * inv * gg[2 * j];
        float xi = y[2 * j + 1] * inv * gg[2 * j + 1];
        float o0 = (xr * fr - xi * fi) * a.scale;
        float o1 = (xr * fi + xi * fr) * a.scale;
        ow[j] = (uint_t)f2b(o0) | ((uint_t)f2b(o1) << 16);
    }
    int h = tid >> 4;
    ushort_t* dst = a.out + ((size_t)((b * 16 + h) * S + s)) * 128 + (tid & 15) * 8;
    *(uint4*)dst = make_uint4(ow[0], ow[1], ow[2], ow[3]);
}

// ---------------- flash attention: 8 waves, 128 q/block, dbuf K/V, packed inputs ----------------
__global__ __launch_bounds__(512, 4) void k_attn(const ushort_t* __restrict__ Q,
                                                 const ushort_t* __restrict__ Kc,
                                                 const ushort_t* __restrict__ Kr,
                                                 const ushort_t* __restrict__ Vt,
                                                 ushort_t* __restrict__ O) {
    __shared__ __align__(16) char sm[65536];
    int tid = threadIdx.x, lane = tid & 63, w = tid >> 6;
    int c = lane & 15, g = lane >> 4;

    int bid = blockIdx.x;
    int xcd = bid & 7, idx = bid >> 3;
    int combo = idx & 3, qt = idx >> 2;
    int b = combo >> 1, h = xcd * 2 + (combo & 1);
    int bh = b * 16 + h;

    const ushort_t* qg = Q + ((size_t)(bh * 2048 + qt * 128 + w * 16 + c)) * 128 + g * 8;
    bf16x8 aQ[4];
#pragma unroll
    for (int ks = 0; ks < 4; ks++) aQ[ks] = *(const bf16x8*)(qg + ks * 32);

    int kbase[4], vbase[8];
#pragma unroll
    for (int n = 0; n < 4; n++) {
        int row = ((n >> 1) << 5) + ((c >> 2) << 3) + ((n & 1) << 2) + (c & 3);
        int sw = (row & 3) | (((row >> 3) & 3) << 2);
        kbase[n] = row * 256 + ((g ^ sw) << 4);
    }
#pragma unroll
    for (int dt = 0; dt < 8; dt++) {
        int vrow = dt * 16 + c;
        vbase[dt] = vrow * 128 + ((g ^ (vrow & 7)) << 4);
    }

    int swk = (lane >> 4) | ((w & 3) << 2);
    int klo = (8 * w + (lane >> 4)) * 256 + (((lane & 15) ^ swk) << 4);
    int vlo = (16 * w + (lane >> 3)) * 128 + (((lane & 7) ^ (lane >> 3)) << 4);
    int dst0 = w * 2048;

    const char* kcb = (const char*)Kc + (size_t)bh * 131072;
    const char* krb = (const char*)Kr + (size_t)bh * 131072;
    const char* vtb = (const char*)Vt + (size_t)bh * 262144;

    float mr = -1e30f, lr = 0.f;
    f32x4 o[8];
#pragma unroll
    for (int d = 0; d < 8; d++) o[d] = (f32x4){0, 0, 0, 0};

    auto STAGE = [&](int DB, int t) {
        const char* kg = (t < 8) ? kcb + t * 16384 : krb + (t - 8) * 16384;
        const char* vg = vtb + t * 16384;
        gload_lds16(kg + klo, sm + DB + dst0);
        gload_lds16(kg + klo + 1024, sm + DB + dst0 + 1024);
        gload_lds16(vg + vlo, sm + DB + 16384 + dst0);
        gload_lds16(vg + vlo + 1024, sm + DB + 16384 + dst0 + 1024);
    };

    auto TILE = [&](int DB) {
        f32x4 sT[4];
#pragma unroll
        for (int n = 0; n < 4; n++) sT[n] = (f32x4){0, 0, 0, 0};
#pragma unroll
        for (int n = 0; n < 4; n++)
#pragma unroll
            for (int ks = 0; ks < 4; ks++) {
                bf16x8 aK = *(const bf16x8*)(sm + DB + (kbase[n] ^ (ks << 6)));
                sT[n] = __builtin_amdgcn_mfma_f32_16x16x32_bf16(aK, aQ[ks], sT[n], 0, 0, 0);
            }
        float mloc = sT[0][0];
#pragma unroll
        for (int n = 0; n < 4; n++)
#pragma unroll
            for (int r = 0; r < 4; r++) mloc = fmaxf(mloc, sT[n][r]);
        if (!__all(mloc - mr <= 8.0f)) {
            float mx = fmaxf(mloc, __shfl_xor(mloc, 16, 64));
            mx = fmaxf(mx, __shfl_xor(mx, 32, 64));
            float mn = fmaxf(mr, mx);
            float al = exp2f(mr - mn);
            mr = mn;
            lr *= al;
#pragma unroll
            for (int d = 0; d < 8; d++) o[d] *= al;
        }
        float p[4][4];
        float ps = 0.f;
#pragma unroll
        for (int n = 0; n < 4; n++)
#pragma unroll
            for (int r = 0; r < 4; r++) {
                p[n][r] = exp2f(sT[n][r] - mr);
                ps += p[n][r];
            }
        lr += ps;
#pragma unroll
        for (int kk = 0; kk < 2; kk++) {
            union { uint_t u[4]; bf16x8 v; } bP;
            bP.u[0] = cvt_pk_bf16(p[2 * kk][0], p[2 * kk][1]);
            bP.u[1] = cvt_pk_bf16(p[2 * kk][2], p[2 * kk][3]);
            bP.u[2] = cvt_pk_bf16(p[2 * kk + 1][0], p[2 * kk + 1][1]);
            bP.u[3] = cvt_pk_bf16(p[2 * kk + 1][2], p[2 * kk + 1][3]);
#pragma unroll
            for (int dt = 0; dt < 8; dt++) {
                bf16x8 aV = *(const bf16x8*)(sm + DB + 16384 + (vbase[dt] ^ (kk << 6)));
                o[dt] = __builtin_amdgcn_mfma_f32_16x16x32_bf16(aV, bP.v, o[dt], 0, 0, 0);
            }
        }
    };

    STAGE(0, 0);
    __syncthreads();
#pragma unroll 1
    for (int t = 0; t < 16; t += 2) {
        STAGE(32768, t + 1);
        TILE(0);
        __syncthreads();
        if (t < 14) STAGE(0, t + 2);
        TILE(32768);
        __syncthreads();
    }

    lr += __shfl_xor(lr, 16, 64);
    lr += __shfl_xor(lr, 32, 64);
    float inv = 1.0f / lr;
    ushort_t* lO = (ushort_t*)sm;
#pragma unroll
    for (int dt = 0; dt < 8; dt++) {
        uint2 wv;
        wv.x = (uint_t)f2b(o[dt][0] * inv) | ((uint_t)f2b(o[dt][1] * inv) << 16);
        wv.y = (uint_t)f2b(o[dt][2] * inv) | ((uint_t)f2b(o[dt][3] * inv) << 16);
        *(uint2*)(lO + (w * 16 + c) * 136 + dt * 16 + g * 4) = wv;
    }
    __syncthreads();
    int row = tid >> 2, c8 = tid & 3;
    const ushort_t* src = lO + row * 136 + c8 * 32;
    ushort_t* dst = O + (size_t)(b * 2048 + qt * 128 + row) * 2048 + h * 128 + c8 * 32;
#pragma unroll
    for (int k = 0; k < 4; k++) *(uint4*)(dst + k * 8) = *(const uint4*)(src + k * 8);
}

extern "C" void kernel_launch(void* const* d_in, const int* in_sizes, int n_in,
                              void* d_out, int out_size, void* d_ws, size_t ws_size,
                              hipStream_t stream) {
    const float* x   = (const float*)d_in[0];
    const float* cam = (const float*)d_in[1];
    const float* ren = (const float*)d_in[2];
    const float* fx  = (const float*)d_in[3];
    const float* fc  = (const float*)d_in[4];
    const float* fr  = (const float*)d_in[5];
    const float* wq  = (const float*)d_in[6];
    const float* bq  = (const float*)d_in[7];
    const float* wk  = (const float*)d_in[8];
    const float* bk  = (const float*)d_in[9];
    const float* wv  = (const float*)d_in[10];
    const float* bv  = (const float*)d_in[11];
    const float* wkr = (const float*)d_in[12];
    const float* bkr = (const float*)d_in[13];
    const float* wvr = (const float*)d_in[14];
    const float* bvr = (const float*)d_in[15];
    const float* wo  = (const float*)d_in[16];
    const float* bo  = (const float*)d_in[17];
    const float* gq  = (const float*)d_in[18];
    const float* gk  = (const float*)d_in[19];

    char* ws = (char*)d_ws;
    ushort_t* wq_b     = (ushort_t*)(ws + 0);
    ushort_t* wk_b     = (ushort_t*)(ws + 8388608);    // wk||wv contiguous (N=4096)
    ushort_t* wkr_b    = (ushort_t*)(ws + 25165824);   // wkr||wvr contiguous
    ushort_t* wo_b     = (ushort_t*)(ws + 41943040);
    ushort_t* xb       = (ushort_t*)(ws + 50331648);   // reused by attn_bf later
    ushort_t* camb     = (ushort_t*)(ws + 67108864);
    ushort_t* renb     = (ushort_t*)(ws + 71303168);
    ushort_t* kcam_lin = (ushort_t*)(ws + 75497472);   // bf16 [1024][2048]
    ushort_t* kren_lin = (ushort_t*)(ws + 79691776);
    ushort_t* vt       = (ushort_t*)(ws + 83886080);   // tile-major V, 8MB
    ushort_t* q_bf     = (ushort_t*)(ws + 92274688);   // packed [b,h,2048,128]
    ushort_t* kcam_bf  = (ushort_t*)(ws + 109051904);  // packed [b,h,512,128]
    ushort_t* kren_bf  = (ushort_t*)(ws + 113246208);
    ushort_t* attn_bf  = (ushort_t*)(ws + 50331648);   // overlays dead xb
    ushort_t* q_lin    = (ushort_t*)d_out;             // d_out doubles as bf16 Q-proj scratch

    hipFuncSetAttribute(reinterpret_cast<const void*>(&k_g256),
                        hipFuncAttributeMaxDynamicSharedMemorySize, 131072);
    hipFuncSetAttribute(reinterpret_cast<const void*>(&k_g128),
                        hipFuncAttributeMaxDynamicSharedMemorySize, 98304);

    // all fp32 -> bf16 converts (weights + activations) in one dispatch
    ushort_t* wv_b  = wk_b + 4194304;
    ushort_t* wvr_b = wkr_b + 4194304;
    Cvt9 c9;
    c9.s[0] = wq;  c9.d[0] = wq_b;  c9.n[0] = 4194304;
    c9.s[1] = wk;  c9.d[1] = wk_b;  c9.n[1] = 4194304;
    c9.s[2] = wv;  c9.d[2] = wv_b;  c9.n[2] = 4194304;
    c9.s[3] = wkr; c9.d[3] = wkr_b; c9.n[3] = 4194304;
    c9.s[4] = wvr; c9.d[4] = wvr_b; c9.n[4] = 4194304;
    c9.s[5] = wo;  c9.d[5] = wo_b;  c9.n[5] = 4194304;
    c9.s[6] = x;   c9.d[6] = xb;    c9.n[6] = 8388608;
    c9.s[7] = cam; c9.d[7] = camb;  c9.n[7] = 2097152;
    c9.s[8] = ren; c9.d[8] = renb;  c9.n[8] = 2097152;
    k_cvt9<<<dim3(2048, 9), 256, 0, stream>>>(c9);

    // merged Q + K/V projections (8-phase 256^2, 512 thr, 256 blocks); V lands in vt
    G8 qa{xb, wq_b, bq, nullptr, (void*)q_lin, nullptr};
    G8 kva0{camb, wk_b, bk, bv, (void*)kcam_lin, (void*)vt};
    G8 kva1{renb, wkr_b, bkr, bvr, (void*)kren_lin, (void*)vt};
    k_g256<<<dim3(256, 1, 1), 512, 131072, stream>>>(qa, kva0, kva1);

    // merged RMSNorm+RoPE (Q folds (1/sqrt(HD))*log2(e)); outputs packed per-head
    RR r0{q_lin, gq, fx, q_bf, 11, 0.08838834764831845f * 1.4426950408889634f};
    RR r1{kcam_lin, gk, fc, kcam_bf, 9, 1.0f};
    RR r2{kren_lin, gk, fr, kren_bf, 9, 1.0f};
    k_rr<<<dim3(6144, 1, 1), 256, 0, stream>>>(r0, r1, r2);

    // flash attention (flat 512, XCD-pinned, contiguous staging)
    k_attn<<<dim3(512, 1, 1), 512, 0, stream>>>(q_bf, kcam_bf, kren_bf, vt, attn_bf);

    // output projection -> d_out (fp32), 8-phase 128x256, 256 blocks
    G8 oa{attn_bf, wo_b, bo, nullptr, d_out, nullptr};
    k_g128<<<dim3(256, 1, 1), 512, 98304, stream>>>(oa);
}

// Round 14
// 201.797 us; speedup vs baseline: 1.0473x; 1.0157x over previous
//
#include <hip/hip_runtime.h>

typedef short bf16x8 __attribute__((ext_vector_type(8)));
typedef float f32x4 __attribute__((ext_vector_type(4)));
typedef unsigned short ushort_t;
typedef unsigned int uint_t;

#define DIM 2048
#define NH 16
#define HD 128

__device__ __forceinline__ ushort_t f2b(float f) {
    union { float f; uint_t u; } a; a.f = f;
    uint_t u = a.u;
    return (ushort_t)((u + 0x7fffu + ((u >> 16) & 1u)) >> 16);
}

__device__ __forceinline__ float b2f(ushort_t s) {
    union { uint_t u; float f; } a; a.u = ((uint_t)s) << 16;
    return a.f;
}

__device__ __forceinline__ uint_t cvt_pk_bf16(float lo, float hi) {
    uint_t r;
    asm("v_cvt_pk_bf16_f32 %0, %1, %2" : "=v"(r) : "v"(lo), "v"(hi));
    return r;
}

__device__ __forceinline__ void gload_lds16(const void* g, void* l) {
    void* gg = const_cast<void*>(g);
    __builtin_amdgcn_global_load_lds(
        (__attribute__((address_space(1))) uint_t*)gg,
        (__attribute__((address_space(3))) uint_t*)l, 16, 0, 0);
}

// ---------------- all fp32->bf16 converts in ONE dispatch ----------------
struct Cvt9 { const float* s[9]; ushort_t* d[9]; int n[9]; };
__global__ __launch_bounds__(256) void k_cvt9(Cvt9 a) {
    int y = blockIdx.y;
    const float* in = a.s[y];
    ushort_t* out = a.d[y];
    int n = a.n[y];
    for (int idx = (blockIdx.x * 256 + threadIdx.x) * 8; idx < n; idx += 2048 * 256 * 8) {
        float4 p = *(const float4*)(in + idx);
        float4 q = *(const float4*)(in + idx + 4);
        uint4 o;
        o.x = (uint_t)f2b(p.x) | ((uint_t)f2b(p.y) << 16);
        o.y = (uint_t)f2b(p.z) | ((uint_t)f2b(p.w) << 16);
        o.z = (uint_t)f2b(q.x) | ((uint_t)f2b(q.y) << 16);
        o.w = (uint_t)f2b(q.z) | ((uint_t)f2b(q.w) << 16);
        *(uint4*)(out + idx) = o;
    }
}

struct G8 {
    const ushort_t* A;
    const ushort_t* B;
    const float* bias0;
    const float* bias1;
    void* out0;
    void* out1;
};

// ======== 8-phase 256x256x(BK=64) bf16 NT GEMM (merged QKV), 512 thr, 128KB LDS ========
__global__ __launch_bounds__(512, 2) void k_g256(G8 p0, G8 p1, G8 p2) {
    extern __shared__ __align__(16) char sm[];
    int tid = threadIdx.x, lane = tid & 63, w = tid >> 6;
    int c = lane & 15, g = lane >> 4;
    int wr = w >> 2, wc = w & 3;

    int flat = blockIdx.x;
    G8 ar;
    int bm, bn, isKV = 0, kvoff = 0;
    {
        int re = (flat & 7) * 32 + (flat >> 3);
        if (re < 128) { ar = p0; bm = re & 15; bn = re >> 4; }
        else {
            int r2 = re - 128;
            int z = r2 >> 6; r2 &= 63;
            ar = z ? p2 : p1;
            bm = r2 & 3; bn = r2 >> 2;
            isKV = 1; kvoff = z ? 512 : 0;
        }
    }

    int wj0 = 2 * w, wj1 = 2 * w + 1;
    int l3 = lane >> 3;
    int swz = ((lane & 7) ^ l3) << 4;
    int RA0 = (wj0 >> 3) * 128 + (wj0 & 7) * 8 + l3;
    int RA1 = (wj1 >> 3) * 128 + (wj1 & 7) * 8 + l3;
    int LB0 = wj0 * 8 + l3;
    int LB1 = wj1 * 8 + l3;
    int RB0 = (LB0 >> 5) * 64 + (LB0 & 15) * 2 + ((LB0 >> 4) & 1);
    int RB1 = (LB1 >> 5) * 64 + (LB1 & 15) * 2 + ((LB1 >> 4) & 1);
    const char* sA0 = (const char*)ar.A + (size_t)(bm * 256 + RA0) * 4096 + swz;
    const char* sA1 = (const char*)ar.A + (size_t)(bm * 256 + RA1) * 4096 + swz;
    const char* sB0 = (const char*)ar.B + (size_t)(bn * 256 + RB0) * 4096 + swz;
    const char* sB1 = (const char*)ar.B + (size_t)(bn * 256 + RB1) * 4096 + swz;
    char* dA0 = sm + wj0 * 1024;
    char* dA1 = sm + wj1 * 1024;
    char* dB0 = sm + 32768 + wj0 * 1024;
    char* dB1 = sm + 32768 + wj1 * 1024;

    auto SA = [&](int buf, int half, int t) {
        gload_lds16(sA0 + (size_t)half * 262144 + t * 128, dA0 + buf + half * 16384);
        gload_lds16(sA1 + (size_t)half * 262144 + t * 128, dA1 + buf + half * 16384);
    };
    auto SB = [&](int buf, int half, int t) {
        gload_lds16(sB0 + (size_t)half * 131072 + t * 128, dB0 + buf + half * 16384);
        gload_lds16(sB1 + (size_t)half * 131072 + t * 128, dB1 + buf + half * 16384);
    };

    int bKS0 = (g << 4) ^ ((c & 7) << 4);
    int bKS1 = (64 | (g << 4)) ^ ((c & 7) << 4);
    int aoffL = wr * 8192 + c * 128;
    int boffL = 32768 + wc * 4096 + c * 128;

    f32x4 acc[8][4];
#pragma unroll
    for (int m = 0; m < 8; m++)
#pragma unroll
        for (int n = 0; n < 4; n++) acc[m][n] = (f32x4){0.f, 0.f, 0.f, 0.f};

    bf16x8 aF[4][2], bF0[2][2], bF1[2][2];

    auto RA = [&](int buf, int mh) {
#pragma unroll
        for (int m = 0; m < 4; m++) {
            aF[m][0] = *(const bf16x8*)(sm + buf + mh * 16384 + aoffL + m * 2048 + bKS0);
            aF[m][1] = *(const bf16x8*)(sm + buf + mh * 16384 + aoffL + m * 2048 + bKS1);
        }
    };
    auto RB = [&](int buf, int nh, bf16x8 (&bF)[2][2]) {
#pragma unroll
        for (int n = 0; n < 2; n++) {
            bF[n][0] = *(const bf16x8*)(sm + buf + boffL + nh * 16384 + n * 2048 + bKS0);
            bF[n][1] = *(const bf16x8*)(sm + buf + boffL + nh * 16384 + n * 2048 + bKS1);
        }
    };
    auto MF = [&](int mh, int nh, bf16x8 (&bF)[2][2]) {
        __builtin_amdgcn_s_setprio(1);
#pragma unroll
        for (int m = 0; m < 4; m++)
#pragma unroll
            for (int n = 0; n < 2; n++)
#pragma unroll
                for (int ks = 0; ks < 2; ks++)
                    acc[mh * 4 + m][nh * 2 + n] = __builtin_amdgcn_mfma_f32_16x16x32_bf16(
                        aF[m][ks], bF[n][ks], acc[mh * 4 + m][nh * 2 + n], 0, 0, 0);
        __builtin_amdgcn_s_setprio(0);
    };

    SA(0, 0, 0); SB(0, 0, 0); SA(0, 1, 0); SB(0, 1, 0);
    SA(65536, 0, 1); SB(65536, 0, 1);
    asm volatile("s_waitcnt vmcnt(8)" ::: "memory");
    __builtin_amdgcn_s_barrier();

#pragma unroll 1
    for (int i = 0; i < 16; ++i) {
        int Tb  = 2 * i + 1;
        int Ta2 = (2 * i + 2 > 31) ? 31 : 2 * i + 2;
        int Tb2 = (2 * i + 3 > 31) ? 31 : 2 * i + 3;
        // p1
        RA(0, 0); RB(0, 0, bF0);
        SA(65536, 1, Tb);
        __builtin_amdgcn_s_barrier();
        MF(0, 0, bF0);
        asm volatile("s_waitcnt vmcnt(6)" ::: "memory");
        __builtin_amdgcn_s_barrier();
        // p2
        RB(0, 1, bF1);
        SB(65536, 1, Tb);
        __builtin_amdgcn_s_barrier();
        MF(0, 1, bF1);
        __builtin_amdgcn_s_barrier();
        // p3
        RA(0, 1);
        SA(0, 0, Ta2);
        __builtin_amdgcn_s_barrier();
        MF(1, 0, bF0);
        __builtin_amdgcn_s_barrier();
        // p4
        SB(0, 0, Ta2);
        __builtin_amdgcn_s_barrier();
        MF(1, 1, bF1);
        asm volatile("s_waitcnt vmcnt(8)" ::: "memory");
        __builtin_amdgcn_s_barrier();
        // p5
        RA(65536, 0); RB(65536, 0, bF0);
        SA(0, 1, Ta2);
        __builtin_amdgcn_s_barrier();
        MF(0, 0, bF0);
        asm volatile("s_waitcnt vmcnt(6)" ::: "memory");
        __builtin_amdgcn_s_barrier();
        // p6
        RB(65536, 1, bF1);
        SB(0, 1, Ta2);
        __builtin_amdgcn_s_barrier();
        MF(0, 1, bF1);
        __builtin_amdgcn_s_barrier();
        // p7
        RA(65536, 1);
        SA(65536, 0, Tb2);
        __builtin_amdgcn_s_barrier();
        MF(1, 0, bF0);
        __builtin_amdgcn_s_barrier();
        // p8
        SB(65536, 0, Tb2);
        __builtin_amdgcn_s_barrier();
        MF(1, 1, bF1);
        asm volatile("s_waitcnt vmcnt(8)" ::: "memory");
        __builtin_amdgcn_s_barrier();
    }

    int orow0 = bm * 256 + wr * 128 + g * 4;
    int colb0 = bn * 256 + wc * 64 + c * 2;
    if (!isKV || bn < 8) {
        ushort_t* o0 = (ushort_t*)ar.out0;
#pragma unroll
        for (int nh = 0; nh < 2; nh++) {
            int colb = colb0 + nh * 32;
            float2 bv = *(const float2*)(ar.bias0 + colb);
#pragma unroll
            for (int m = 0; m < 8; m++)
#pragma unroll
                for (int q = 0; q < 4; q++) {
                    uint_t pk = cvt_pk_bf16(acc[m][nh * 2][q] + bv.x,
                                            acc[m][nh * 2 + 1][q] + bv.y);
                    *(uint_t*)(o0 + (size_t)(orow0 + m * 16 + q) * 2048 + colb) = pk;
                }
        }
    } else {
        ushort_t* o1 = (ushort_t*)ar.out1;
#pragma unroll
        for (int nh = 0; nh < 2; nh++)
#pragma unroll
            for (int np = 0; np < 2; np++) {
                int col2 = colb0 + nh * 32 + np - 2048;
                int h = col2 >> 7, d = col2 & 127;
                float bvs = ar.bias1[col2];
#pragma unroll
                for (int m = 0; m < 8; m++) {
                    int r = orow0 + m * 16;
                    int bb = r >> 9;
                    int kvg = kvoff + (r & 511);
                    int t = kvg >> 6, ki = kvg & 63;
                    uint2 wv;
                    wv.x = cvt_pk_bf16(acc[m][nh * 2 + np][0] + bvs, acc[m][nh * 2 + np][1] + bvs);
                    wv.y = cvt_pk_bf16(acc[m][nh * 2 + np][2] + bvs, acc[m][nh * 2 + np][3] + bvs);
                    *(uint2*)(o1 + (size_t)((bb * 16 + h) * 16 + t) * 8192 + d * 64 + ki) = wv;
                }
            }
    }
}

// ======== 8-phase 128x256x(BK=64) bf16 NT GEMM (out-proj), 512 thr, 96KB LDS, fp32 out ========
__global__ __launch_bounds__(512, 2) void k_g128(G8 p0) {
    extern __shared__ __align__(16) char sm[];
    int tid = threadIdx.x, lane = tid & 63, w = tid >> 6;
    int c = lane & 15, g = lane >> 4;
    int wr = w >> 2, wc = w & 3;

    int flat = blockIdx.x;
    int re = (flat & 7) * 32 + (flat >> 3);
    int bm = re & 31, bn = re >> 5;
    G8 ar = p0;

    int l3 = lane >> 3;
    int swz = ((lane & 7) ^ l3) << 4;
    int wj0 = 2 * w, wj1 = 2 * w + 1;
    int LB0 = wj0 * 8 + l3;
    int LB1 = wj1 * 8 + l3;
    int RB0 = (LB0 >> 5) * 64 + (LB0 & 15) * 2 + ((LB0 >> 4) & 1);
    int RB1 = (LB1 >> 5) * 64 + (LB1 & 15) * 2 + ((LB1 >> 4) & 1);
    const char* sA  = (const char*)ar.A + (size_t)(bm * 128 + w * 8 + l3) * 4096 + swz;
    const char* sB0 = (const char*)ar.B + (size_t)(bn * 256 + RB0) * 4096 + swz;
    const char* sB1 = (const char*)ar.B + (size_t)(bn * 256 + RB1) * 4096 + swz;
    char* dA  = sm + w * 1024;
    char* dB0 = sm + 16384 + wj0 * 1024;
    char* dB1 = sm + 16384 + wj1 * 1024;

    auto SA = [&](int buf, int half, int t) {
        gload_lds16(sA + (size_t)half * 262144 + t * 128, dA + buf + half * 8192);
    };
    auto SB = [&](int buf, int half, int t) {
        gload_lds16(sB0 + (size_t)half * 131072 + t * 128, dB0 + buf + half * 16384);
        gload_lds16(sB1 + (size_t)half * 131072 + t * 128, dB1 + buf + half * 16384);
    };

    int bKS0 = (g << 4) ^ ((c & 7) << 4);
    int bKS1 = (64 | (g << 4)) ^ ((c & 7) << 4);
    int aoffL = wr * 8192 + c * 128;
    int boffL = 16384 + wc * 4096 + c * 128;

    f32x4 acc[4][4];
#pragma unroll
    for (int m = 0; m < 4; m++)
#pragma unroll
        for (int n = 0; n < 4; n++) acc[m][n] = (f32x4){0.f, 0.f, 0.f, 0.f};

    bf16x8 aF[2][2], bF0[2][2], bF1[2][2];

    auto RA = [&](int buf, int mhp) {
#pragma unroll
        for (int m = 0; m < 2; m++) {
            aF[m][0] = *(const bf16x8*)(sm + buf + aoffL + (mhp * 2 + m) * 2048 + bKS0);
            aF[m][1] = *(const bf16x8*)(sm + buf + aoffL + (mhp * 2 + m) * 2048 + bKS1);
        }
    };
    auto RB = [&](int buf, int nh, bf16x8 (&bF)[2][2]) {
#pragma unroll
        for (int n = 0; n < 2; n++) {
            bF[n][0] = *(const bf16x8*)(sm + buf + boffL + nh * 16384 + n * 2048 + bKS0);
            bF[n][1] = *(const bf16x8*)(sm + buf + boffL + nh * 16384 + n * 2048 + bKS1);
        }
    };
    auto MF = [&](int mhp, int nh, bf16x8 (&bF)[2][2]) {
        __builtin_amdgcn_s_setprio(1);
#pragma unroll
        for (int m = 0; m < 2; m++)
#pragma unroll
            for (int n = 0; n < 2; n++)
#pragma unroll
                for (int ks = 0; ks < 2; ks++)
                    acc[mhp * 2 + m][nh * 2 + n] = __builtin_amdgcn_mfma_f32_16x16x32_bf16(
                        aF[m][ks], bF[n][ks], acc[mhp * 2 + m][nh * 2 + n], 0, 0, 0);
        __builtin_amdgcn_s_setprio(0);
    };

    const int B1 = 49152;
    SA(0, 0, 0); SA(0, 1, 0); SB(0, 0, 0); SB(0, 1, 0);
    SA(B1, 0, 1);
    asm volatile("s_waitcnt vmcnt(1)" ::: "memory");
    __builtin_amdgcn_s_barrier();

#pragma unroll 1
    for (int i = 0; i < 16; ++i) {
        int Tb  = 2 * i + 1;
        int Ta2 = (2 * i + 2 > 31) ? 31 : 2 * i + 2;
        int Tb2 = (2 * i + 3 > 31) ? 31 : 2 * i + 3;
        // p1
        RA(0, 0); RB(0, 0, bF0);
        SA(B1, 1, Tb);
        __builtin_amdgcn_s_barrier();
        MF(0, 0, bF0);
        __builtin_amdgcn_s_barrier();
        // p2
        RB(0, 1, bF1);
        SB(B1, 0, Tb);
        __builtin_amdgcn_s_barrier();
        MF(0, 1, bF1);
        __builtin_amdgcn_s_barrier();
        // p3
        RA(0, 1);
        SB(B1, 1, Tb);
        __builtin_amdgcn_s_barrier();
        MF(1, 0, bF0);
        __builtin_amdgcn_s_barrier();
        // p4
        SA(0, 0, Ta2);
        __builtin_amdgcn_s_barrier();
        MF(1, 1, bF1);
        asm volatile("s_waitcnt vmcnt(3)" ::: "memory");
        __builtin_amdgcn_s_barrier();
        // p5
        RA(B1, 0); RB(B1, 0, bF0);
        SA(0, 1, Ta2);
        __builtin_amdgcn_s_barrier();
        MF(0, 0, bF0);
        asm volatile("s_waitcnt vmcnt(2)" ::: "memory");
        __builtin_amdgcn_s_barrier();
        // p6
        RB(B1, 1, bF1);
        SB(0, 0, Ta2);
        __builtin_amdgcn_s_barrier();
        MF(0, 1, bF1);
        __builtin_amdgcn_s_barrier();
        // p7
        RA(B1, 1);
        SB(0, 1, Ta2);
        __builtin_amdgcn_s_barrier();
        MF(1, 0, bF0);
        __builtin_amdgcn_s_barrier();
        // p8
        SA(B1, 0, Tb2);
        __builtin_amdgcn_s_barrier();
        MF(1, 1, bF1);
        asm volatile("s_waitcnt vmcnt(1)" ::: "memory");
        __builtin_amdgcn_s_barrier();
    }

    int orow0 = bm * 128 + wr * 64 + g * 4;
    int colb0 = bn * 256 + wc * 64 + c * 2;
    float* o0 = (float*)ar.out0;
#pragma unroll
    for (int nh = 0; nh < 2; nh++) {
        int colb = colb0 + nh * 32;
        float2 bv = *(const float2*)(ar.bias0 + colb);
#pragma unroll
        for (int m = 0; m < 4; m++)
#pragma unroll
            for (int q = 0; q < 4; q++) {
                float2 st = {acc[m][nh * 2][q] + bv.x, acc[m][nh * 2 + 1][q] + bv.y};
                *(float2*)(o0 + (size_t)(orow0 + m * 16 + q) * 2048 + colb) = st;
            }
    }
}

// ---------------- merged RMSNorm + RoPE: bf16 row-major in -> packed [b,h,s,128] bf16 out ----------------
struct RR { const ushort_t* in; const float* gain; const float* freqs; ushort_t* out; int lgS; float scale; };
__global__ __launch_bounds__(256) void k_rr(RR a0, RR a1, RR a2) {
    int bid = blockIdx.x;
    RR a; int row;
    if (bid < 4096) { a = a0; row = bid; }
    else if (bid < 5120) { a = a1; row = bid - 4096; }
    else { a = a2; row = bid - 5120; }
    int S = 1 << a.lgS;
    int s = row & (S - 1);
    int b = row >> a.lgS;
    int tid = threadIdx.x;
    uint4 v = *(const uint4*)(a.in + (size_t)row * 2048 + tid * 8);
    ushort_t us[8];
    us[0] = (ushort_t)(v.x & 0xffff); us[1] = (ushort_t)(v.x >> 16);
    us[2] = (ushort_t)(v.y & 0xffff); us[3] = (ushort_t)(v.y >> 16);
    us[4] = (ushort_t)(v.z & 0xffff); us[5] = (ushort_t)(v.z >> 16);
    us[6] = (ushort_t)(v.w & 0xffff); us[7] = (ushort_t)(v.w >> 16);
    float y[8];
#pragma unroll
    for (int j = 0; j < 8; j++) y[j] = b2f(us[j]);
    float ss = 0.f;
#pragma unroll
    for (int j = 0; j < 8; j++) ss += y[j] * y[j];
#pragma unroll
    for (int off = 32; off > 0; off >>= 1) ss += __shfl_xor(ss, off, 64);
    __shared__ float red[4];
    int lane = tid & 63, wid = tid >> 6;
    if (lane == 0) red[wid] = ss;
    __syncthreads();
    float tot = red[0] + red[1] + red[2] + red[3];
    float inv = rsqrtf(tot * (1.0f / DIM) + 1e-6f);
    const float* gp = a.gain + tid * 8;
    float4 g0 = *(const float4*)gp;
    float4 g1 = *(const float4*)(gp + 4);
    float gg[8] = {g0.x, g0.y, g0.z, g0.w, g1.x, g1.y, g1.z, g1.w};
    int p0 = (tid * 8 & 127) >> 1;
    const float* fq = a.freqs + ((size_t)s * 64 + p0) * 2;
    uint_t ow[4];
#pragma unroll
    for (int j = 0; j < 4; j++) {
        float fr = fq[j * 2 + 0], fi = fq[j * 2 + 1];
        float xr = y[2 * j] * inv * gg[2 * j];
        float xi = y[2 * j + 1] * inv * gg[2 * j + 1];
        float o0 = (xr * fr - xi * fi) * a.scale;
        float o1 = (xr * fi + xi * fr) * a.scale;
        ow[j] = (uint_t)f2b(o0) | ((uint_t)f2b(o1) << 16);
    }
    int h = tid >> 4;
    ushort_t* dst = a.out + ((size_t)((b * 16 + h) * S + s)) * 128 + (tid & 15) * 8;
    *(uint4*)dst = make_uint4(ow[0], ow[1], ow[2], ow[3]);
}

// ---------------- flash attention: 16 waves, 256 q/block, dbuf K/V, packed inputs ----------------
// Q packed [b,h,2048,128]; K packed [b,h,512,128] (cam/ren); V tile-major [b,h,t][128][64].
// Grid 256 (1/CU): per-CU KV staging volume halved vs 128-row blocks.
__global__ __launch_bounds__(1024, 1) void k_attn(const ushort_t* __restrict__ Q,
                                                  const ushort_t* __restrict__ Kc,
                                                  const ushort_t* __restrict__ Kr,
                                                  const ushort_t* __restrict__ Vt,
                                                  ushort_t* __restrict__ O) {
    __shared__ __align__(16) char sm[65536];
    int tid = threadIdx.x, lane = tid & 63, w = tid >> 6;   // w in 0..15
    int c = lane & 15, g = lane >> 4;
    int l3 = lane >> 3;

    int bid = blockIdx.x;
    int xcd = bid & 7, idx = bid >> 3;
    int combo = idx & 3, qt = idx >> 2;    // qt in 0..7 (256 q-rows each)
    int b = combo >> 1, h = xcd * 2 + (combo & 1);
    int bh = b * 16 + h;

    const ushort_t* qg = Q + ((size_t)(bh * 2048 + qt * 256 + w * 16 + c)) * 128 + g * 8;
    bf16x8 aQ[4];
#pragma unroll
    for (int ks = 0; ks < 4; ks++) aQ[ks] = *(const bf16x8*)(qg + ks * 32);

    int kbase[4], vbase[8];
#pragma unroll
    for (int n = 0; n < 4; n++) {
        int row = ((n >> 1) << 5) + ((c >> 2) << 3) + ((n & 1) << 2) + (c & 3);
        int sw = (row & 3) | (((row >> 3) & 3) << 2);
        kbase[n] = row * 256 + ((g ^ sw) << 4);
    }
#pragma unroll
    for (int dt = 0; dt < 8; dt++) {
        int vrow = dt * 16 + c;
        vbase[dt] = vrow * 128 + ((g ^ (vrow & 7)) << 4);
    }

    // staging: wave w owns K rows 4w..4w+3 (R=4w+g) and V rows 8w..8w+7 (Rv=8w+l3)
    // write-side swizzle = sw_read(R): K -> g | (((w>>1)&3)<<2); V -> l3 (rows mod 8)
    int swk = g | (((w >> 1) & 3) << 2);
    int klo = (4 * w + g) * 256 + (((lane & 15) ^ swk) << 4);
    int vlo = (8 * w + l3) * 128 + (((lane & 7) ^ l3) << 4);
    int dst0 = w * 1024;

    const char* kcb = (const char*)Kc + (size_t)bh * 131072;
    const char* krb = (const char*)Kr + (size_t)bh * 131072;
    const char* vtb = (const char*)Vt + (size_t)bh * 262144;

    float mr = -1e30f, lr = 0.f;
    f32x4 o[8];
#pragma unroll
    for (int d = 0; d < 8; d++) o[d] = (f32x4){0, 0, 0, 0};

    auto STAGE = [&](int DB, int t) {
        const char* kg = (t < 8) ? kcb + t * 16384 : krb + (t - 8) * 16384;
        const char* vg = vtb + t * 16384;
        gload_lds16(kg + klo, sm + DB + dst0);
        gload_lds16(vg + vlo, sm + DB + 16384 + dst0);
    };

    auto TILE = [&](int DB) {
        f32x4 sT[4];
#pragma unroll
        for (int n = 0; n < 4; n++) sT[n] = (f32x4){0, 0, 0, 0};
#pragma unroll
        for (int n = 0; n < 4; n++)
#pragma unroll
            for (int ks = 0; ks < 4; ks++) {
                bf16x8 aK = *(const bf16x8*)(sm + DB + (kbase[n] ^ (ks << 6)));
                sT[n] = __builtin_amdgcn_mfma_f32_16x16x32_bf16(aK, aQ[ks], sT[n], 0, 0, 0);
            }
        float mloc = sT[0][0];
#pragma unroll
        for (int n = 0; n < 4; n++)
#pragma unroll
            for (int r = 0; r < 4; r++) mloc = fmaxf(mloc, sT[n][r]);
        if (!__all(mloc - mr <= 8.0f)) {
            float mx = fmaxf(mloc, __shfl_xor(mloc, 16, 64));
            mx = fmaxf(mx, __shfl_xor(mx, 32, 64));
            float mn = fmaxf(mr, mx);
            float al = exp2f(mr - mn);
            mr = mn;
            lr *= al;
#pragma unroll
            for (int d = 0; d < 8; d++) o[d] *= al;
        }
        float p[4][4];
        float ps = 0.f;
#pragma unroll
        for (int n = 0; n < 4; n++)
#pragma unroll
            for (int r = 0; r < 4; r++) {
                p[n][r] = exp2f(sT[n][r] - mr);
                ps += p[n][r];
            }
        lr += ps;
#pragma unroll
        for (int kk = 0; kk < 2; kk++) {
            union { uint_t u[4]; bf16x8 v; } bP;
            bP.u[0] = cvt_pk_bf16(p[2 * kk][0], p[2 * kk][1]);
            bP.u[1] = cvt_pk_bf16(p[2 * kk][2], p[2 * kk][3]);
            bP.u[2] = cvt_pk_bf16(p[2 * kk + 1][0], p[2 * kk + 1][1]);
            bP.u[3] = cvt_pk_bf16(p[2 * kk + 1][2], p[2 * kk + 1][3]);
#pragma unroll
            for (int dt = 0; dt < 8; dt++) {
                bf16x8 aV = *(const bf16x8*)(sm + DB + 16384 + (vbase[dt] ^ (kk << 6)));
                o[dt] = __builtin_amdgcn_mfma_f32_16x16x32_bf16(aV, bP.v, o[dt], 0, 0, 0);
            }
        }
    };

    STAGE(0, 0);
    __syncthreads();
#pragma unroll 1
    for (int t = 0; t < 16; t += 2) {
        STAGE(32768, t + 1);
        TILE(0);
        __syncthreads();
        if (t < 14) STAGE(0, t + 2);
        TILE(32768);
        __syncthreads();
    }

    lr += __shfl_xor(lr, 16, 64);
    lr += __shfl_xor(lr, 32, 64);
    float inv = 1.0f / lr;
    ushort_t* lO = (ushort_t*)sm;
    // two-pass epilogue through [128][136] LDS staging (fits 34.8KB)
#pragma unroll
    for (int pass = 0; pass < 2; ++pass) {
        if ((w >> 3) == pass) {
#pragma unroll
            for (int dt = 0; dt < 8; dt++) {
                uint2 wv;
                wv.x = (uint_t)f2b(o[dt][0] * inv) | ((uint_t)f2b(o[dt][1] * inv) << 16);
                wv.y = (uint_t)f2b(o[dt][2] * inv) | ((uint_t)f2b(o[dt][3] * inv) << 16);
                *(uint2*)(lO + ((w & 7) * 16 + c) * 136 + dt * 16 + g * 4) = wv;
            }
        }
        __syncthreads();
        int row = tid >> 3, c8 = tid & 7;
        const ushort_t* src = lO + row * 136 + c8 * 16;
        ushort_t* dst = O + (size_t)(b * 2048 + qt * 256 + pass * 128 + row) * 2048 + h * 128 + c8 * 16;
        *(uint4*)dst = *(const uint4*)src;
        *(uint4*)(dst + 8) = *(const uint4*)(src + 8);
        __syncthreads();
    }
}

extern "C" void kernel_launch(void* const* d_in, const int* in_sizes, int n_in,
                              void* d_out, int out_size, void* d_ws, size_t ws_size,
                              hipStream_t stream) {
    const float* x   = (const float*)d_in[0];
    const float* cam = (const float*)d_in[1];
    const float* ren = (const float*)d_in[2];
    const float* fx  = (const float*)d_in[3];
    const float* fc  = (const float*)d_in[4];
    const float* fr  = (const float*)d_in[5];
    const float* wq  = (const float*)d_in[6];
    const float* bq  = (const float*)d_in[7];
    const float* wk  = (const float*)d_in[8];
    const float* bk  = (const float*)d_in[9];
    const float* wv  = (const float*)d_in[10];
    const float* bv  = (const float*)d_in[11];
    const float* wkr = (const float*)d_in[12];
    const float* bkr = (const float*)d_in[13];
    const float* wvr = (const float*)d_in[14];
    const float* bvr = (const float*)d_in[15];
    const float* wo  = (const float*)d_in[16];
    const float* bo  = (const float*)d_in[17];
    const float* gq  = (const float*)d_in[18];
    const float* gk  = (const float*)d_in[19];

    char* ws = (char*)d_ws;
    ushort_t* wq_b     = (ushort_t*)(ws + 0);
    ushort_t* wk_b     = (ushort_t*)(ws + 8388608);    // wk||wv contiguous (N=4096)
    ushort_t* wkr_b    = (ushort_t*)(ws + 25165824);   // wkr||wvr contiguous
    ushort_t* wo_b     = (ushort_t*)(ws + 41943040);
    ushort_t* xb       = (ushort_t*)(ws + 50331648);   // reused by attn_bf later
    ushort_t* camb     = (ushort_t*)(ws + 67108864);
    ushort_t* renb     = (ushort_t*)(ws + 71303168);
    ushort_t* kcam_lin = (ushort_t*)(ws + 75497472);   // bf16 [1024][2048]
    ushort_t* kren_lin = (ushort_t*)(ws + 79691776);
    ushort_t* vt       = (ushort_t*)(ws + 83886080);   // tile-major V, 8MB
    ushort_t* q_bf     = (ushort_t*)(ws + 92274688);   // packed [b,h,2048,128]
    ushort_t* kcam_bf  = (ushort_t*)(ws + 109051904);  // packed [b,h,512,128]
    ushort_t* kren_bf  = (ushort_t*)(ws + 113246208);
    ushort_t* attn_bf  = (ushort_t*)(ws + 50331648);   // overlays dead xb
    ushort_t* q_lin    = (ushort_t*)d_out;             // d_out doubles as bf16 Q-proj scratch

    hipFuncSetAttribute(reinterpret_cast<const void*>(&k_g256),
                        hipFuncAttributeMaxDynamicSharedMemorySize, 131072);
    hipFuncSetAttribute(reinterpret_cast<const void*>(&k_g128),
                        hipFuncAttributeMaxDynamicSharedMemorySize, 98304);

    // all fp32 -> bf16 converts (weights + activations) in one dispatch
    ushort_t* wv_b  = wk_b + 4194304;
    ushort_t* wvr_b = wkr_b + 4194304;
    Cvt9 c9;
    c9.s[0] = wq;  c9.d[0] = wq_b;  c9.n[0] = 4194304;
    c9.s[1] = wk;  c9.d[1] = wk_b;  c9.n[1] = 4194304;
    c9.s[2] = wv;  c9.d[2] = wv_b;  c9.n[2] = 4194304;
    c9.s[3] = wkr; c9.d[3] = wkr_b; c9.n[3] = 4194304;
    c9.s[4] = wvr; c9.d[4] = wvr_b; c9.n[4] = 4194304;
    c9.s[5] = wo;  c9.d[5] = wo_b;  c9.n[5] = 4194304;
    c9.s[6] = x;   c9.d[6] = xb;    c9.n[6] = 8388608;
    c9.s[7] = cam; c9.d[7] = camb;  c9.n[7] = 2097152;
    c9.s[8] = ren; c9.d[8] = renb;  c9.n[8] = 2097152;
    k_cvt9<<<dim3(2048, 9), 256, 0, stream>>>(c9);

    // merged Q + K/V projections (8-phase 256^2, 512 thr, 256 blocks); V lands in vt
    G8 qa{xb, wq_b, bq, nullptr, (void*)q_lin, nullptr};
    G8 kva0{camb, wk_b, bk, bv, (void*)kcam_lin, (void*)vt};
    G8 kva1{renb, wkr_b, bkr, bvr, (void*)kren_lin, (void*)vt};
    k_g256<<<dim3(256, 1, 1), 512, 131072, stream>>>(qa, kva0, kva1);

    // merged RMSNorm+RoPE (Q folds (1/sqrt(HD))*log2(e)); outputs packed per-head
    RR r0{q_lin, gq, fx, q_bf, 11, 0.08838834764831845f * 1.4426950408889634f};
    RR r1{kcam_lin, gk, fc, kcam_bf, 9, 1.0f};
    RR r2{kren_lin, gk, fr, kren_bf, 9, 1.0f};
    k_rr<<<dim3(6144, 1, 1), 256, 0, stream>>>(r0, r1, r2);

    // flash attention (grid 256, 1024 thr, 256 q-rows/block, XCD-pinned)
    k_attn<<<dim3(256, 1, 1), 1024, 0, stream>>>(q_bf, kcam_bf, kren_bf, vt, attn_bf);

    // output projection -> d_out (fp32), 8-phase 128x256, 256 blocks
    G8 oa{attn_bf, wo_b, bo, nullptr, d_out, nullptr};
    k_g128<<<dim3(256, 1, 1), 512, 98304, stream>>>(oa);
}